// Round 13
// baseline (12736.462 us; speedup 1.0000x reference)
//
#include <hip/hip_runtime.h>
#include <hip/hip_cooperative_groups.h>
#include <math.h>

namespace cg = cooperative_groups;

#define B 32
#define T 128
#define H 512
#define E 512
#define ODIM 256
#define STEPS 16
#define G3 1536
#define BH (B * H)
#define NBLK 256
#define NTHR 512

typedef float4 f4;
typedef unsigned int uint32;
typedef unsigned short ushort;

__device__ __forceinline__ float sigmoidf_(float x) { return 1.0f / (1.0f + __expf(-x)); }
__device__ __forceinline__ float tanh_fast(float x) {
    float t = __expf(-2.0f * fabsf(x));
    float r = (1.0f - t) / (1.0f + t);
    return __builtin_copysignf(r, x);
}
__device__ __forceinline__ float dot4(const f4 a, const f4 b) {
    return fmaf(a.x, b.x, fmaf(a.y, b.y, fmaf(a.z, b.z, a.w * b.w)));
}
__device__ __forceinline__ void bf2x(uint32 v, float& lo, float& hi) {
    union { uint32 u; float f; } a, b;
    a.u = v << 16; b.u = v & 0xffff0000u;
    lo = a.f; hi = b.f;
}
__device__ __forceinline__ float dot8bf(uint4 wv, const f4 hA, const f4 hB) {
    float w0, w1, w2, w3, w4, w5, w6, w7;
    bf2x(wv.x, w0, w1); bf2x(wv.y, w2, w3); bf2x(wv.z, w4, w5); bf2x(wv.w, w6, w7);
    float s = fmaf(w0, hA.x, w1 * hA.y);
    s = fmaf(w2, hA.z, s); s = fmaf(w3, hA.w, s);
    s = fmaf(w4, hB.x, s); s = fmaf(w5, hB.y, s);
    s = fmaf(w6, hB.z, s); s = fmaf(w7, hB.w, s);
    return s;
}
__device__ __forceinline__ ushort f2bf(float f) {
    union { float f; uint32 u; } a; a.f = f;
    uint32 r = a.u + 0x7fffu + ((a.u >> 16) & 1u);
    return (ushort)(r >> 16);
}

// ---- staging helpers (nthr-parameterized) ----
__device__ __forceinline__ void stage_b32(const float* __restrict__ src, float* __restrict__ st,
                                          int tid, int nthr) {
    f4* d = (f4*)st;
    const f4* s = (const f4*)src;
    for (int idx = tid; idx < 4096; idx += nthr) {
        int b = idx >> 7, kq = idx & 127;
        d[kq * 32 + (b ^ (kq & 31))] = s[idx];
    }
}
__device__ __forceinline__ f4 ldb32(const float* __restrict__ st, int kq, int b) {
    return ((const f4*)st)[kq * 32 + (b ^ (kq & 31))];
}
#define A0(kq, b) ((kq) * 4 + ((kq) >> 3) + (b))
#define ST4_SZ 544  // f4 slots per 4-batch stage (2176 floats)
__device__ __forceinline__ void stage4(const float* __restrict__ src, float* __restrict__ st,
                                       int tid, int nthr) {
    f4* d = (f4*)st;
    const f4* s = (const f4*)src;
    for (int idx = tid; idx < 512; idx += nthr) {
        int b = idx >> 7, kq = idx & 127;
        d[A0(kq, b)] = s[idx];
    }
}

// ---------------- pre-kernels ----------------
__global__ void cvt_bf16_kernel(const float* __restrict__ src, ushort* __restrict__ dst, int n4) {
    int i = blockIdx.x * 256 + threadIdx.x;
    if (i < n4) {
        f4 v = ((const f4*)src)[i];
        ushort4 o;
        o.x = f2bf(v.x); o.y = f2bf(v.y); o.z = f2bf(v.z); o.w = f2bf(v.w);
        ((ushort4*)dst)[i] = o;
    }
}

__global__ void transpose_kernel(const float* __restrict__ in, float* __restrict__ out,
                                 int R, int C, int ldin) {
    __shared__ float tile[32][33];
    int r0 = blockIdx.x * 32, c0 = blockIdx.y * 32;
    int tx = threadIdx.x & 31, ty = threadIdx.x >> 5;
#pragma unroll
    for (int k = 0; k < 4; ++k) {
        int r = r0 + ty + k * 8;
        tile[ty + k * 8][tx] = in[(size_t)r * ldin + c0 + tx];
    }
    __syncthreads();
#pragma unroll
    for (int k = 0; k < 4; ++k) {
        int c = c0 + ty + k * 8;
        out[(size_t)c * R + r0 + tx] = tile[tx][ty + k * 8];
    }
}

__global__ void __launch_bounds__(256) kproj_gemm_kernel(const float* __restrict__ A,
                                                         const float* __restrict__ Bt,
                                                         float* __restrict__ kpT) {
    __shared__ float As[64][68];
    __shared__ float Bs[64][64];
    int r0 = blockIdx.x * 64, c0 = blockIdx.y * 64;
    int tid = threadIdx.x;
    int tx = tid & 15, ty = tid >> 4;
    float acc[4][4] = {};
    for (int k0 = 0; k0 < 512; k0 += 64) {
#pragma unroll
        for (int i = 0; i < 4; ++i) {
            int row = i * 16 + ty, col = tx * 4;
            f4 av = *(const f4*)(A + (size_t)(r0 + row) * 512 + k0 + col);
            As[row][col] = av.x; As[row][col + 1] = av.y; As[row][col + 2] = av.z; As[row][col + 3] = av.w;
            f4 bv = *(const f4*)(Bt + (size_t)(k0 + row) * 512 + c0 + col);
            *(f4*)&Bs[row][col] = bv;
        }
        __syncthreads();
#pragma unroll 8
        for (int kk = 0; kk < 64; ++kk) {
            float a[4];
#pragma unroll
            for (int i = 0; i < 4; ++i) a[i] = As[ty * 4 + i][kk];
            f4 bv = *(const f4*)&Bs[kk][tx * 4];
#pragma unroll
            for (int i = 0; i < 4; ++i) {
                acc[i][0] += a[i] * bv.x; acc[i][1] += a[i] * bv.y;
                acc[i][2] += a[i] * bv.z; acc[i][3] += a[i] * bv.w;
            }
        }
        __syncthreads();
    }
#pragma unroll
    for (int i = 0; i < 4; ++i) {
        int r = r0 + ty * 4 + i;
        int b = r >> 7, t = r & 127;
#pragma unroll
        for (int j = 0; j < 4; ++j) {
            int c = c0 + tx * 4 + j;
            kpT[((size_t)b * H + c) * T + t] = acc[i][j];
        }
    }
}

// ================= FALLBACK multi-launch kernels (r10 verbatim) =================
__global__ void __launch_bounds__(512) init_kernel(const float* __restrict__ hidden,
                                                   const float* __restrict__ emb_W,
                                                   const float* __restrict__ emb_b,
                                                   float* __restrict__ h0, float* __restrict__ h1,
                                                   float* __restrict__ inp) {
    int b = blockIdx.x, tid = threadIdx.x;
    h0[b * H + tid] = hidden[b * H + tid];
    h1[b * H + tid] = hidden[BH + b * H + tid];
    if (b == 0) {
        const f4* row = (const f4*)(emb_W + (size_t)tid * ODIM);
        float acc = emb_b[tid];
#pragma unroll 8
        for (int o = 0; o < 64; ++o) { f4 v = row[o]; acc += v.x + v.y + v.z + v.w; }
        for (int bb = 0; bb < B; ++bb) inp[bb * E + tid] = acc;
    }
}

__global__ void __launch_bounds__(256) attn1_kernel(
    int nb_q, const float* __restrict__ h1cur, const float* __restrict__ Wq,
    float* __restrict__ q, const float* __restrict__ last_W, const float* __restrict__ last_b,
    const float* __restrict__ target_step, const int* __restrict__ mask_step,
    float* __restrict__ f, float* __restrict__ out_step) {
    __shared__ float sh[16384];
    int tid = threadIdx.x;
    stage_b32(h1cur, sh, tid, 256);
    __syncthreads();
    if ((int)blockIdx.x < nb_q) {
        int jg = blockIdx.x * 8 + (tid & 7), b = tid >> 3;
        const f4* w = (const f4*)(Wq + (size_t)jg * H);
        float acc = 0.f;
#pragma unroll 8
        for (int kq = 0; kq < 128; ++kq) acc += dot4(w[kq], ldb32(sh, kq, b));
        q[b * H + jg] = acc;
    } else {
        int og = (blockIdx.x - nb_q) * 8 + (tid & 7), b = tid >> 3;
        const f4* w = (const f4*)(last_W + (size_t)og * H);
        float acc = 0.f;
#pragma unroll 8
        for (int kq = 0; kq < 128; ++kq) acc += dot4(w[kq], ldb32(sh, kq, b));
        float lin = acc + last_b[og];
        float ff = mask_step[b] ? target_step[b * ODIM + og] : lin;
        f[b * ODIM + og] = ff;
        out_step[b * ODIM + og] = ff;
    }
}

__global__ void __launch_bounds__(256) attn2_kernel(
    const float* __restrict__ q, const float* __restrict__ kpT, const float* __restrict__ wv,
    float* __restrict__ spart, const float* __restrict__ f, const float* __restrict__ emb_W,
    const float* __restrict__ emb_b, float* __restrict__ inp) {
    __shared__ float sm[8704];
    int tid = threadIdx.x;
    if ((int)blockIdx.x < 256) {
        int b = blockIdx.x >> 3, js = blockIdx.x & 7;
        float* qs = sm;
        float* ws_ = sm + 64;
        float* part = sm + 128;
        if (tid < 64) {
            qs[tid] = q[b * H + js * 64 + tid];
            ws_[tid] = wv[js * 64 + tid];
        }
        __syncthreads();
        int t = tid & 127, jh = tid >> 7;
        const float* kp = kpT + ((size_t)b * H + js * 64 + jh * 32) * T + t;
        float sa = 0.f;
#pragma unroll 8
        for (int jj = 0; jj < 32; ++jj) {
            int j = jh * 32 + jj;
            sa += tanh_fast(qs[j] + kp[(size_t)jj * T]) * ws_[j];
        }
        part[tid] = sa;
        __syncthreads();
        if (tid < 128) spart[((size_t)b * 8 + js) * T + tid] = part[tid] + part[128 + tid];
    } else {
        float* st = sm;
        {
            f4* d = (f4*)st;
            const f4* s = (const f4*)f;
            for (int idx = tid; idx < 2048; idx += 256) {
                int b = idx >> 6, oq = idx & 63;
                d[oq * 32 + (b ^ (oq & 31))] = s[idx];
            }
        }
        __syncthreads();
        int eg = (blockIdx.x - 256) * 16 + (tid & 15), bq = tid >> 4;
        const f4* w = (const f4*)(emb_W + (size_t)eg * ODIM);
        float a0 = 0.f, a1 = 0.f;
#pragma unroll 4
        for (int oq = 0; oq < 64; ++oq) {
            f4 wv_ = w[oq];
            a0 += dot4(wv_, ((const f4*)st)[oq * 32 + (bq ^ (oq & 31))]);
            a1 += dot4(wv_, ((const f4*)st)[oq * 32 + ((bq + 16) ^ (oq & 31))]);
        }
        float eb = emb_b[eg];
        inp[bq * E + eg] = a0 + eb;
        inp[(bq + 16) * E + eg] = a1 + eb;
    }
}

__global__ void __launch_bounds__(256) attn3_kernel(
    const float* __restrict__ spart, const float* __restrict__ enc,
    float* __restrict__ ctx, float* __restrict__ attn_out) {
    __shared__ float sw[T];
    __shared__ float red[4];
    __shared__ float part[256];
    int tid = threadIdx.x;
    int b = blockIdx.x >> 3, cs = blockIdx.x & 7;
    float sv = 0.f;
    if (tid < 128) {
        const float* sp = spart + (size_t)b * 8 * T + tid;
#pragma unroll
        for (int js = 0; js < 8; ++js) sv += sp[js * T];
        float m = sv;
        for (int off = 32; off; off >>= 1) m = fmaxf(m, __shfl_xor(m, off));
        if ((tid & 63) == 0) red[tid >> 6] = m;
    }
    __syncthreads();
    if (tid < 128) {
        float M = fmaxf(red[0], red[1]);
        float e = __expf(sv - M);
        sw[tid] = e;
        float s = e;
        for (int off = 32; off; off >>= 1) s += __shfl_xor(s, off);
        if ((tid & 63) == 0) red[2 + (tid >> 6)] = s;
    }
    __syncthreads();
    if (tid < 128) {
        float w = sw[tid] / (red[2] + red[3]);
        sw[tid] = w;
        if (cs == 0) attn_out[(size_t)b * T + tid] = w;
    }
    __syncthreads();
    int c = tid & 63, tq = tid >> 6;
    int cg = cs * 64 + c;
    const float* ep = enc + ((size_t)b * T + tq * 32) * H + cg;
    float acc = 0.f;
#pragma unroll 8
    for (int t2 = 0; t2 < 32; ++t2) acc += sw[tq * 32 + t2] * ep[(size_t)t2 * H];
    part[tid] = acc;
    __syncthreads();
    if (tid < 64) ctx[(size_t)b * H + cg] = part[tid] + part[64 + tid] + part[128 + tid] + part[192 + tid];
}

__global__ void __launch_bounds__(256) gi_kernel(
    const float* __restrict__ ctx, const float* __restrict__ inp,
    const ushort* __restrict__ Wi0bf, const float* __restrict__ bi0,
    float* __restrict__ gi_ctx, float* __restrict__ gi_emb_i) {
    __shared__ float sh[16384];
    int tid = threadIdx.x;
    bool isC = (int)blockIdx.x < 96;
    int lb = isC ? blockIdx.x : blockIdx.x - 96;
    stage_b32(isC ? ctx : inp, sh, tid, 256);
    __syncthreads();
    int cg = lb * 16 + (tid & 15), bq = tid >> 4;
    const uint4* w = (const uint4*)(Wi0bf + (size_t)cg * 1024 + (isC ? 0 : 512));
    float a0 = 0.f, a1 = 0.f;
#pragma unroll 4
    for (int it = 0; it < 64; ++it) {
        uint4 wv_ = w[it];
        f4 hA0 = ldb32(sh, it * 2, bq), hB0 = ldb32(sh, it * 2 + 1, bq);
        f4 hA1 = ldb32(sh, it * 2, bq + 16), hB1 = ldb32(sh, it * 2 + 1, bq + 16);
        a0 += dot8bf(wv_, hA0, hB0);
        a1 += dot8bf(wv_, hA1, hB1);
    }
    float bias = isC ? bi0[cg] : 0.f;
    float* dst = isC ? gi_ctx : gi_emb_i;
    dst[(size_t)bq * G3 + cg] = a0 + bias;
    dst[(size_t)(bq + 16) * G3 + cg] = a1 + bias;
}

__global__ void __launch_bounds__(256) cell_kernel(
    int nb0, const float* __restrict__ h0_src, float* __restrict__ h0_dst,
    const float* __restrict__ h1_src, float* __restrict__ h1_dst,
    const float* __restrict__ gi_emb_t, const float* __restrict__ gi_ctx,
    const ushort* __restrict__ Wh0bf, const float* __restrict__ bh0,
    const ushort* __restrict__ Wi1bf, const float* __restrict__ bi1,
    const ushort* __restrict__ Wh1bf, const float* __restrict__ bh1) {
    __shared__ __align__(16) float sh[7936];
    int tid = threadIdx.x;
    if ((int)blockIdx.x < nb0) {
        int jc = blockIdx.x & 31, bg = blockIdx.x >> 5;
        int j0 = jc * 16, b0 = bg * 4;
        stage4(h0_src + (size_t)b0 * H, sh, tid, 256);
        __syncthreads();
        int j = tid & 15, ks = tid >> 4, jg = j0 + j;
        const uint4* w0 = (const uint4*)(Wh0bf + (size_t)jg * 512) + ks * 4;
        const uint4* w1 = (const uint4*)(Wh0bf + (size_t)(512 + jg) * 512) + ks * 4;
        const uint4* w2 = (const uint4*)(Wh0bf + (size_t)(1024 + jg) * 512) + ks * 4;
        float a0[4] = {}, a1[4] = {}, a2[4] = {};
#pragma unroll
        for (int c = 0; c < 4; ++c) {
            uint4 u0 = w0[c], u1 = w1[c], u2 = w2[c];
            int kq = ks * 8 + c * 2;
#pragma unroll
            for (int b = 0; b < 4; ++b) {
                f4 hA = ((const f4*)sh)[A0(kq, b)];
                f4 hB = ((const f4*)sh)[A0(kq + 1, b)];
                a0[b] += dot8bf(u0, hA, hB);
                a1[b] += dot8bf(u1, hA, hB);
                a2[b] += dot8bf(u2, hA, hB);
            }
        }
        float* part = sh + ST4_SZ * 4;
        {
            float* p = part + (size_t)tid * 13;
#pragma unroll
            for (int b = 0; b < 4; ++b) { p[b] = a0[b]; p[4 + b] = a1[b]; p[8 + b] = a2[b]; }
        }
        __syncthreads();
        if (tid < 64) {
            int fj = tid & 15, fb = tid >> 4;
            int jg2 = j0 + fj, bg2 = b0 + fb;
            float s0 = 0.f, s1 = 0.f, s2 = 0.f;
#pragma unroll
            for (int k2 = 0; k2 < 16; ++k2) {
                const float* p = part + (size_t)(k2 * 16 + fj) * 13;
                s0 += p[fb]; s1 += p[4 + fb]; s2 += p[8 + fb];
            }
            const float* gc = gi_ctx + (size_t)bg2 * G3;
            const float* ge = gi_emb_t + (size_t)bg2 * G3;
            float r_ = sigmoidf_(gc[jg2] + ge[jg2] + s0 + bh0[jg2]);
            float z_ = sigmoidf_(gc[H + jg2] + ge[H + jg2] + s1 + bh0[H + jg2]);
            float n_ = tanh_fast(gc[2 * H + jg2] + ge[2 * H + jg2] + r_ * (s2 + bh0[2 * H + jg2]));
            f4 hp = ((const f4*)sh)[A0(jg2 >> 2, fb)];
            float hprev = ((const float*)&hp)[jg2 & 3];
            h0_dst[(size_t)bg2 * H + jg2] = (1.f - z_) * n_ + z_ * hprev;
        }
    } else {
        int lb = blockIdx.x - nb0;
        int jc = lb & 31, bg = lb >> 5;
        int j0 = jc * 16, b0 = bg * 4;
        float* stX = sh;
        float* stH = sh + ST4_SZ * 4;
        stage4(h0_src + (size_t)b0 * H, stX, tid, 256);
        stage4(h1_src + (size_t)b0 * H, stH, tid, 256);
        __syncthreads();
        int j = tid & 15, ks = (tid >> 4) & 7, m = tid >> 7, jg = j0 + j;
        const ushort* Wm = m ? Wh1bf : Wi1bf;
        const float* stm = m ? stH : stX;
        const uint4* w0 = (const uint4*)(Wm + (size_t)jg * 512) + ks * 8;
        const uint4* w1 = (const uint4*)(Wm + (size_t)(512 + jg) * 512) + ks * 8;
        const uint4* w2 = (const uint4*)(Wm + (size_t)(1024 + jg) * 512) + ks * 8;
        float a0[4] = {}, a1[4] = {}, a2[4] = {};
#pragma unroll
        for (int c = 0; c < 8; ++c) {
            uint4 u0 = w0[c], u1 = w1[c], u2 = w2[c];
            int kq = ks * 16 + c * 2;
#pragma unroll
            for (int b = 0; b < 4; ++b) {
                f4 hA = ((const f4*)stm)[A0(kq, b)];
                f4 hB = ((const f4*)stm)[A0(kq + 1, b)];
                a0[b] += dot8bf(u0, hA, hB);
                a1[b] += dot8bf(u1, hA, hB);
                a2[b] += dot8bf(u2, hA, hB);
            }
        }
        float* part = sh + ST4_SZ * 8;
        {
            float* p = part + (size_t)tid * 13;
#pragma unroll
            for (int b = 0; b < 4; ++b) { p[b] = a0[b]; p[4 + b] = a1[b]; p[8 + b] = a2[b]; }
        }
        __syncthreads();
        if (tid < 64) {
            int fj = tid & 15, fb = tid >> 4;
            int jg2 = j0 + fj, bg2 = b0 + fb;
            float i0 = 0.f, i1 = 0.f, i2 = 0.f, g0 = 0.f, g1 = 0.f, g2 = 0.f;
#pragma unroll
            for (int k2 = 0; k2 < 8; ++k2) {
                const float* pi = part + (size_t)(k2 * 16 + fj) * 13;
                const float* ph = part + (size_t)((128 + k2 * 16 + fj)) * 13;
                i0 += pi[fb]; i1 += pi[4 + fb]; i2 += pi[8 + fb];
                g0 += ph[fb]; g1 += ph[4 + fb]; g2 += ph[8 + fb];
            }
            float r_ = sigmoidf_(i0 + bi1[jg2] + g0 + bh1[jg2]);
            float z_ = sigmoidf_(i1 + bi1[H + jg2] + g1 + bh1[H + jg2]);
            float n_ = tanh_fast(i2 + bi1[2 * H + jg2] + r_ * (g2 + bh1[2 * H + jg2]));
            f4 hp = ((const f4*)stH)[A0(jg2 >> 2, fb)];
            float hprev = ((const float*)&hp)[jg2 & 3];
            h1_dst[(size_t)bg2 * H + jg2] = (1.f - z_) * n_ + z_ * hprev;
        }
    }
}

__global__ void copy_hidden_kernel(const float* __restrict__ h0, const float* __restrict__ h1,
                                   float* __restrict__ dst) {
    int i = blockIdx.x * 256 + threadIdx.x;
    dst[i] = h0[i];
    dst[BH + i] = h1[i];
}

// ================= persistent cooperative decoder (r6 launch config) =================
__global__ void __launch_bounds__(NTHR, 2) decoder_kernel(
    const float* __restrict__ enc, const float* __restrict__ hidden,
    const float* __restrict__ target, const float* __restrict__ Wq,
    const float* __restrict__ wv, const float* __restrict__ emb_W,
    const float* __restrict__ emb_b, const float* __restrict__ bi0,
    const float* __restrict__ bh0, const float* __restrict__ bi1,
    const float* __restrict__ bh1, const float* __restrict__ last_W,
    const float* __restrict__ last_b, const int* __restrict__ tmask,
    const float* __restrict__ kpT, const ushort* __restrict__ Wi0bf,
    const ushort* __restrict__ Wh0bf, const ushort* __restrict__ Wi1bf,
    const ushort* __restrict__ Wh1bf,
    float* __restrict__ out, float* __restrict__ out_hidden, float* __restrict__ out_attn,
    float* __restrict__ h0buf, float* __restrict__ h1buf,
    float* __restrict__ gi_emb, float* __restrict__ gi_ctx,
    float* __restrict__ qbuf, float* __restrict__ ctxbuf, float* __restrict__ fbuf,
    float* __restrict__ inpbuf, float* __restrict__ spart) {
    cg::grid_group grid = cg::this_grid();
    __shared__ __align__(16) float smem[16384];  // 64 KB
    const int tid = threadIdx.x, bid = blockIdx.x;

    // ======== INIT ========
    if (bid < 8) {
        ((f4*)h0buf)[bid * 512 + tid] = ((const f4*)hidden)[bid * 512 + tid];
    } else if (bid < 16) {
        int idx = (bid - 8) * 512 + tid;
        ((f4*)h1buf)[idx] = ((const f4*)(hidden + BH))[idx];
    } else if (bid == 16) {
        const f4* row = (const f4*)(emb_W + (size_t)tid * ODIM);
        float acc = emb_b[tid];
#pragma unroll 8
        for (int o = 0; o < 64; ++o) { f4 v = row[o]; acc += v.x + v.y + v.z + v.w; }
        for (int b = 0; b < B; ++b) inpbuf[b * E + tid] = acc;
    }
    grid.sync();

    int p0 = 0, p1 = 0;
    for (int i = 0; i < STEPS; ++i) {
        const float* h1cur = h1buf + (size_t)p1 * BH;
        // ======== PH_A: qproj (0-31) + lin(i-1) (32-47) ========
        if (bid < 32) {
            stage_b32(h1cur, smem, tid, NTHR);
            __syncthreads();
            int jg = bid * 16 + (tid & 15), b = tid >> 4;
            const f4* w = (const f4*)(Wq + (size_t)jg * H);
            float acc = 0.f;
#pragma unroll 8
            for (int kq = 0; kq < 128; ++kq) acc += dot4(w[kq], ldb32(smem, kq, b));
            qbuf[b * H + jg] = acc;
        } else if (bid < 48 && i > 0) {
            stage_b32(h1cur, smem, tid, NTHR);
            __syncthreads();
            int og = (bid - 32) * 16 + (tid & 15), b = tid >> 4;
            const f4* w = (const f4*)(last_W + (size_t)og * H);
            float acc = 0.f;
#pragma unroll 8
            for (int kq = 0; kq < 128; ++kq) acc += dot4(w[kq], ldb32(smem, kq, b));
            float lin = acc + last_b[og];
            float ff = tmask[(i - 1) * B + b] ? target[((size_t)(i - 1) * B + b) * ODIM + og] : lin;
            fbuf[b * ODIM + og] = ff;
            out[((size_t)(i - 1) * B + b) * ODIM + og] = ff;
        }
        grid.sync();
        // ======== PH_B: score partials (all 256 blocks) ========
        {
            int b = bid >> 3, js = bid & 7;
            float* qs = smem;
            float* ws_ = smem + 64;
            float* part = smem + 128;
            if (tid < 64) {
                qs[tid] = qbuf[b * H + js * 64 + tid];
                ws_[tid] = wv[js * 64 + tid];
            }
            __syncthreads();
            int t = tid & 127, jh = tid >> 7;  // 4 jh x 16 j
            const float* kp = kpT + ((size_t)b * H + js * 64 + jh * 16) * T + t;
            float sa = 0.f;
#pragma unroll 8
            for (int jj = 0; jj < 16; ++jj) {
                int j = jh * 16 + jj;
                sa += tanh_fast(qs[j] + kp[(size_t)jj * T]) * ws_[j];
            }
            part[tid] = sa;
            __syncthreads();
            if (tid < 128)
                spart[((size_t)b * 8 + js) * T + tid] =
                    part[tid] + part[128 + tid] + part[256 + tid] + part[384 + tid];
        }
        grid.sync();
        // ======== PH_C: softmax+ctx (0-127) + emb(i-1) (128-159) ========
        if (bid < 128) {
            int b = bid >> 2, cs = bid & 3;
            float* sw = smem;          // 128
            float* red = smem + 128;   // 8
            float* part = smem + 136;  // 512
            float sv = 0.f;
            if (tid < 128) {
                const float* sp = spart + (size_t)b * 8 * T + tid;
#pragma unroll
                for (int js = 0; js < 8; ++js) sv += sp[js * T];
                float m = sv;
                for (int off = 32; off; off >>= 1) m = fmaxf(m, __shfl_xor(m, off));
                if ((tid & 63) == 0) red[tid >> 6] = m;
            }
            __syncthreads();
            if (tid < 128) {
                float M = fmaxf(red[0], red[1]);
                float e = __expf(sv - M);
                sw[tid] = e;
                float s = e;
                for (int off = 32; off; off >>= 1) s += __shfl_xor(s, off);
                if ((tid & 63) == 0) red[2 + (tid >> 6)] = s;
            }
            __syncthreads();
            if (tid < 128) {
                float w = sw[tid] / (red[2] + red[3]);
                sw[tid] = w;
                if (cs == 0) out_attn[((size_t)i * B + b) * T + tid] = w;
            }
            __syncthreads();
            int c = tid & 127, tq = tid >> 7;  // 4 tq x 32 t
            int cg = cs * 128 + c;
            const float* ep = enc + ((size_t)b * T + tq * 32) * H + cg;
            float acc = 0.f;
#pragma unroll 8
            for (int t2 = 0; t2 < 32; ++t2) acc += sw[tq * 32 + t2] * ep[(size_t)t2 * H];
            part[tq * 128 + c] = acc;
            __syncthreads();
            if (tid < 128)
                ctxbuf[(size_t)b * H + cg] =
                    part[tid] + part[128 + tid] + part[256 + tid] + part[384 + tid];
        } else if (bid < 160 && i > 0) {
            int lb = bid - 128;
            {
                f4* d = (f4*)smem;
                const f4* s = (const f4*)fbuf;
                for (int idx = tid; idx < 2048; idx += NTHR) {
                    int b = idx >> 6, oq = idx & 63;
                    d[oq * 32 + (b ^ (oq & 31))] = s[idx];
                }
            }
            __syncthreads();
            int eg = lb * 16 + (tid & 15), b = tid >> 4;
            const f4* w = (const f4*)(emb_W + (size_t)eg * ODIM);
            float acc = 0.f;
#pragma unroll 8
            for (int oq = 0; oq < 64; ++oq)
                acc += dot4(w[oq], ((const f4*)smem)[oq * 32 + (b ^ (oq & 31))]);
            inpbuf[b * E + eg] = acc + emb_b[eg];
        }
        grid.sync();
        // ======== PH_D: gi_ctx (0-95) + gi_emb[i] (96-191) ========
        if (bid < 192) {
            bool isC = bid < 96;
            int lb = isC ? bid : bid - 96;
            stage_b32(isC ? ctxbuf : inpbuf, smem, tid, NTHR);
            __syncthreads();
            int cg = lb * 16 + (tid & 15), b = tid >> 4;
            const uint4* w = (const uint4*)(Wi0bf + (size_t)cg * 1024 + (isC ? 0 : 512));
            float acc = 0.f;
#pragma unroll 4
            for (int it = 0; it < 64; ++it) {
                uint4 wv_ = w[it];
                acc += dot8bf(wv_, ldb32(smem, it * 2, b), ldb32(smem, it * 2 + 1, b));
            }
            float* dst = isC ? gi_ctx : (gi_emb + (size_t)i * B * G3);
            dst[(size_t)b * G3 + cg] = acc + (isC ? bi0[cg] : 0.f);
        }
        grid.sync();
        // ======== cells: t = 0..i+1 ; l0 blocks 0-127, l1 blocks 128-255 ========
        for (int t = 0; t <= i + 1; ++t) {
            const float* h0s = h0buf + (size_t)p0 * BH;
            const float* h1s = h1buf + (size_t)p1 * BH;
            float* h0d = h0buf + (size_t)(p0 ^ 1) * BH;
            float* h1d = h1buf + (size_t)(p1 ^ 1) * BH;
            if (bid < 128) {
                if (t <= i) {
                    int jsl = bid >> 2, bg = bid & 3;  // 32 x 16j, 4 x 8b
                    int j0 = jsl * 16, b0 = bg * 8;
                    float* stA = smem;                 // b0..b0+3
                    float* stB = smem + 2176;          // b0+4..b0+7
                    stage4(h0s + (size_t)b0 * H, stA, tid, NTHR);
                    stage4(h0s + (size_t)(b0 + 4) * H, stB, tid, NTHR);
                    __syncthreads();
                    int j = tid & 15, ks = (tid >> 4) & 15, bh = tid >> 8, jg = j0 + j;
                    const float* stm = bh ? stB : stA;
                    const uint4* w0 = (const uint4*)(Wh0bf + (size_t)jg * 512) + ks * 4;
                    const uint4* w1 = (const uint4*)(Wh0bf + (size_t)(512 + jg) * 512) + ks * 4;
                    const uint4* w2 = (const uint4*)(Wh0bf + (size_t)(1024 + jg) * 512) + ks * 4;
                    float a0[4] = {}, a1[4] = {}, a2[4] = {};
#pragma unroll
                    for (int c = 0; c < 4; ++c) {
                        uint4 u0 = w0[c], u1 = w1[c], u2 = w2[c];
                        int kq = ks * 8 + c * 2;
#pragma unroll
                        for (int b = 0; b < 4; ++b) {
                            f4 hA = ((const f4*)stm)[A0(kq, b)];
                            f4 hB = ((const f4*)stm)[A0(kq + 1, b)];
                            a0[b] += dot8bf(u0, hA, hB);
                            a1[b] += dot8bf(u1, hA, hB);
                            a2[b] += dot8bf(u2, hA, hB);
                        }
                    }
                    float* part = smem + 4352;
                    {
                        float* pr = part + (size_t)tid * 13;
#pragma unroll
                        for (int b = 0; b < 4; ++b) { pr[b] = a0[b]; pr[4 + b] = a1[b]; pr[8 + b] = a2[b]; }
                    }
                    __syncthreads();
                    if (tid < 128) {
                        int fj = tid & 15, fb = tid >> 4;  // 16j x 8b
                        int bh2 = fb >> 2, fbi = fb & 3;
                        int jg2 = j0 + fj, bg2 = b0 + fb;
                        float s0 = 0.f, s1 = 0.f, s2 = 0.f;
#pragma unroll
                        for (int k2 = 0; k2 < 16; ++k2) {
                            const float* p = part + (size_t)((bh2 << 8) + (k2 << 4) + fj) * 13;
                            s0 += p[fbi]; s1 += p[4 + fbi]; s2 += p[8 + fbi];
                        }
                        const float* gc = gi_ctx + (size_t)bg2 * G3;
                        const float* ge = gi_emb + ((size_t)t * B + bg2) * G3;
                        float r_ = sigmoidf_(gc[jg2] + ge[jg2] + s0 + bh0[jg2]);
                        float z_ = sigmoidf_(gc[H + jg2] + ge[H + jg2] + s1 + bh0[H + jg2]);
                        float n_ = tanh_fast(gc[2 * H + jg2] + ge[2 * H + jg2] +
                                             r_ * (s2 + bh0[2 * H + jg2]));
                        const float* stm2 = (fb >= 4) ? stB : stA;
                        f4 hp = ((const f4*)stm2)[A0(jg2 >> 2, fb & 3)];
                        float hprev = ((const float*)&hp)[jg2 & 3];
                        h0d[(size_t)bg2 * H + jg2] = (1.f - z_) * n_ + z_ * hprev;
                    }
                }
            } else {
                if (t >= 1) {
                    int lb = bid - 128;
                    int jsl = lb >> 2, bg = lb & 3;
                    int j0 = jsl * 16, b0 = bg * 8;
                    float* stX0 = smem;
                    float* stX1 = smem + 2176;
                    float* stH0 = smem + 4352;
                    float* stH1 = smem + 6528;
                    stage4(h0s + (size_t)b0 * H, stX0, tid, NTHR);
                    stage4(h0s + (size_t)(b0 + 4) * H, stX1, tid, NTHR);
                    stage4(h1s + (size_t)b0 * H, stH0, tid, NTHR);
                    stage4(h1s + (size_t)(b0 + 4) * H, stH1, tid, NTHR);
                    __syncthreads();
                    int j = tid & 15, ks = (tid >> 4) & 7, bh = (tid >> 7) & 1, m = tid >> 8;
                    int jg = j0 + j;
                    const float* stm = m ? (bh ? stH1 : stH0) : (bh ? stX1 : stX0);
                    const ushort* Wm = m ? Wh1bf : Wi1bf;
                    const uint4* w0 = (const uint4*)(Wm + (size_t)jg * 512) + ks * 8;
                    const uint4* w1 = (const uint4*)(Wm + (size_t)(512 + jg) * 512) + ks * 8;
                    const uint4* w2 = (const uint4*)(Wm + (size_t)(1024 + jg) * 512) + ks * 8;
                    float a0[4] = {}, a1[4] = {}, a2[4] = {};
#pragma unroll
                    for (int c = 0; c < 8; ++c) {
                        uint4 u0 = w0[c], u1 = w1[c], u2 = w2[c];
                        int kq = ks * 16 + c * 2;
#pragma unroll
                        for (int b = 0; b < 4; ++b) {
                            f4 hA = ((const f4*)stm)[A0(kq, b)];
                            f4 hB = ((const f4*)stm)[A0(kq + 1, b)];
                            a0[b] += dot8bf(u0, hA, hB);
                            a1[b] += dot8bf(u1, hA, hB);
                            a2[b] += dot8bf(u2, hA, hB);
                        }
                    }
                    float* part = smem + 8704;
                    {
                        float* pr = part + (size_t)tid * 13;
#pragma unroll
                        for (int b = 0; b < 4; ++b) { pr[b] = a0[b]; pr[4 + b] = a1[b]; pr[8 + b] = a2[b]; }
                    }
                    __syncthreads();
                    if (tid < 128) {
                        int fj = tid & 15, fb = tid >> 4;
                        int bh2 = fb >> 2, fbi = fb & 3;
                        int jg2 = j0 + fj, bg2 = b0 + fb;
                        float i0 = 0.f, i1 = 0.f, i2 = 0.f, g0 = 0.f, g1 = 0.f, g2 = 0.f;
#pragma unroll
                        for (int k2 = 0; k2 < 8; ++k2) {
                            const float* pi = part + (size_t)((bh2 << 7) + (k2 << 4) + fj) * 13;
                            const float* ph = part + (size_t)(256 + (bh2 << 7) + (k2 << 4) + fj) * 13;
                            i0 += pi[fbi]; i1 += pi[4 + fbi]; i2 += pi[8 + fbi];
                            g0 += ph[fbi]; g1 += ph[4 + fbi]; g2 += ph[8 + fbi];
                        }
                        float r_ = sigmoidf_(i0 + bi1[jg2] + g0 + bh1[jg2]);
                        float z_ = sigmoidf_(i1 + bi1[H + jg2] + g1 + bh1[H + jg2]);
                        float n_ = tanh_fast(i2 + bi1[2 * H + jg2] + r_ * (g2 + bh1[2 * H + jg2]));
                        const float* stm2 = (fb >= 4) ? stH1 : stH0;
                        f4 hp = ((const f4*)stm2)[A0(jg2 >> 2, fb & 3)];
                        float hprev = ((const float*)&hp)[jg2 & 3];
                        h1d[(size_t)bg2 * H + jg2] = (1.f - z_) * n_ + z_ * hprev;
                    }
                }
            }
            grid.sync();
            if (t <= i) p0 ^= 1;
            if (t >= 1) p1 ^= 1;
        }
    }
    // ======== FINAL: lin(15) + copy hidden ========
    {
        const float* h0s = h0buf + (size_t)p0 * BH;
        const float* h1s = h1buf + (size_t)p1 * BH;
        if (bid >= 32 && bid < 48) {
            stage_b32(h1s, smem, tid, NTHR);
            __syncthreads();
            int og = (bid - 32) * 16 + (tid & 15), b = tid >> 4;
            const f4* w = (const f4*)(last_W + (size_t)og * H);
            float acc = 0.f;
#pragma unroll 8
            for (int kq = 0; kq < 128; ++kq) acc += dot4(w[kq], ldb32(smem, kq, b));
            float lin = acc + last_b[og];
            float ff = tmask[15 * B + b] ? target[((size_t)15 * B + b) * ODIM + og] : lin;
            out[((size_t)15 * B + b) * ODIM + og] = ff;
        } else if (bid < 8) {
            ((f4*)out_hidden)[bid * 512 + tid] = ((const f4*)h0s)[bid * 512 + tid];
        } else if (bid < 16) {
            int idx = (bid - 8) * 512 + tid;
            ((f4*)(out_hidden + BH))[idx] = ((const f4*)h1s)[idx];
        }
    }
}

extern "C" void kernel_launch(void* const* d_in, const int* in_sizes, int n_in,
                              void* d_out_v, int out_size, void* d_ws, size_t ws_size,
                              hipStream_t stream) {
    const float* enc = (const float*)d_in[0];
    const float* hidden = (const float*)d_in[1];
    const float* target = (const float*)d_in[2];
    const float* Wq = (const float*)d_in[3];
    const float* Wk = (const float*)d_in[4];
    const float* wv = (const float*)d_in[5];
    const float* emb_W = (const float*)d_in[6];
    const float* emb_b = (const float*)d_in[7];
    const float* Wi0 = (const float*)d_in[8];
    const float* Wh0 = (const float*)d_in[9];
    const float* bi0 = (const float*)d_in[10];
    const float* bh0 = (const float*)d_in[11];
    const float* Wi1 = (const float*)d_in[12];
    const float* Wh1 = (const float*)d_in[13];
    const float* bi1 = (const float*)d_in[14];
    const float* bh1 = (const float*)d_in[15];
    const float* last_W = (const float*)d_in[16];
    const float* last_b = (const float*)d_in[17];
    const int* tmask = (const int*)d_in[18];

    float* out = (float*)d_out_v;
    float* out_hidden = out + (size_t)STEPS * B * ODIM;
    float* out_attn = out_hidden + (size_t)2 * BH;

    float* ws = (float*)d_ws;
    float* kpT = ws;
    float* WkT = kpT + 2097152;
    float* gi_emb = WkT + 262144;
    float* gi_ctx = gi_emb + 786432;
    float* h0buf = gi_ctx + 49152;
    float* h1buf = h0buf + 32768;
    float* qbuf = h1buf + 32768;
    float* ctxbuf = qbuf + 16384;
    float* fbuf = ctxbuf + 16384;
    float* inpbuf = fbuf + 8192;
    float* spart = inpbuf + 16384;
    ushort* Wi0bf = (ushort*)(spart + 32768);
    ushort* Wh0bf = Wi0bf + 1572864;
    ushort* Wi1bf = Wh0bf + 786432;
    ushort* Wh1bf = Wi1bf + 786432;

    cvt_bf16_kernel<<<1536, 256, 0, stream>>>(Wi0, Wi0bf, 393216);
    cvt_bf16_kernel<<<768, 256, 0, stream>>>(Wh0, Wh0bf, 196608);
    cvt_bf16_kernel<<<768, 256, 0, stream>>>(Wi1, Wi1bf, 196608);
    cvt_bf16_kernel<<<768, 256, 0, stream>>>(Wh1, Wh1bf, 196608);
    transpose_kernel<<<dim3(16, 16), 256, 0, stream>>>(Wk, WkT, 512, 512, 512);
    kproj_gemm_kernel<<<dim3(64, 8), 256, 0, stream>>>(enc, WkT, kpT);

    const float* kpTc = kpT;
    const ushort* Wi0c = Wi0bf;
    const ushort* Wh0c = Wh0bf;
    const ushort* Wi1c = Wi1bf;
    const ushort* Wh1c = Wh1bf;
    void* args[] = {(void*)&enc,    (void*)&hidden, (void*)&target, (void*)&Wq,
                    (void*)&wv,     (void*)&emb_W,  (void*)&emb_b,  (void*)&bi0,
                    (void*)&bh0,    (void*)&bi1,    (void*)&bh1,    (void*)&last_W,
                    (void*)&last_b, (void*)&tmask,  (void*)&kpTc,   (void*)&Wi0c,
                    (void*)&Wh0c,   (void*)&Wi1c,   (void*)&Wh1c,   (void*)&out,
                    (void*)&out_hidden, (void*)&out_attn, (void*)&h0buf, (void*)&h1buf,
                    (void*)&gi_emb, (void*)&gi_ctx, (void*)&qbuf, (void*)&ctxbuf,
                    (void*)&fbuf,   (void*)&inpbuf, (void*)&spart};
    hipError_t cerr = hipLaunchCooperativeKernel((void*)decoder_kernel, dim3(NBLK), dim3(NTHR),
                                                 args, 0, stream);
    if (cerr != hipSuccess) {
        // -------- fallback: r10 multi-launch schedule --------
        init_kernel<<<B, 512, 0, stream>>>(hidden, emb_W, emb_b, h0buf, h1buf, inpbuf);
        int p0 = 0, p1 = 0;
        for (int i = 0; i < STEPS; ++i) {
            int im1 = (i > 0) ? i - 1 : 0;
            const float* h1cur = h1buf + (size_t)p1 * BH;
            attn1_kernel<<<(i > 0) ? 96 : 64, 256, 0, stream>>>(
                64, h1cur, Wq, qbuf, last_W, last_b, target + (size_t)im1 * B * ODIM,
                tmask + im1 * B, fbuf, out + (size_t)im1 * B * ODIM);
            attn2_kernel<<<(i > 0) ? 288 : 256, 256, 0, stream>>>(qbuf, kpT, wv, spart, fbuf,
                                                                  emb_W, emb_b, inpbuf);
            attn3_kernel<<<256, 256, 0, stream>>>(spart, enc, ctxbuf,
                                                  out_attn + (size_t)i * B * T);
            gi_kernel<<<192, 256, 0, stream>>>(ctxbuf, inpbuf, Wi0bf, bi0, gi_ctx,
                                               gi_emb + (size_t)i * B * G3);
            for (int t = 0; t <= i + 1; ++t) {
                int nb0 = (t <= i) ? 256 : 0;
                int nb1 = (t >= 1) ? 256 : 0;
                int tge = (t <= i) ? t : 0;
                cell_kernel<<<nb0 + nb1, 256, 0, stream>>>(
                    nb0, h0buf + (size_t)p0 * BH, h0buf + (size_t)(p0 ^ 1) * BH,
                    h1buf + (size_t)p1 * BH, h1buf + (size_t)(p1 ^ 1) * BH,
                    gi_emb + (size_t)tge * B * G3, gi_ctx, Wh0bf, bh0, Wi1bf, bi1, Wh1bf, bh1);
                if (nb0) p0 ^= 1;
                if (nb1) p1 ^= 1;
            }
        }
        attn1_kernel<<<32, 256, 0, stream>>>(0, h1buf + (size_t)p1 * BH, Wq, qbuf, last_W,
                                             last_b, target + (size_t)15 * B * ODIM,
                                             tmask + 15 * B, fbuf, out + (size_t)15 * B * ODIM);
        copy_hidden_kernel<<<64, 256, 0, stream>>>(h0buf + (size_t)p0 * BH,
                                                   h1buf + (size_t)p1 * BH, out_hidden);
    }
}

// Round 14
// 5980.321 us; speedup vs baseline: 2.1297x; 2.1297x over previous
//
#include <hip/hip_runtime.h>
#include <math.h>

#define B 32
#define T 128
#define H 512
#define E 512
#define ODIM 256
#define STEPS 16
#define G3 1536
#define BH (B * H)

typedef float4 f4;
typedef unsigned int uint32;
typedef unsigned short ushort;

__device__ __forceinline__ float sigmoidf_(float x) { return 1.0f / (1.0f + __expf(-x)); }
__device__ __forceinline__ float tanh_fast(float x) {
    float t = __expf(-2.0f * fabsf(x));
    float r = (1.0f - t) / (1.0f + t);
    return __builtin_copysignf(r, x);
}
__device__ __forceinline__ float dot4(const f4 a, const f4 b) {
    return fmaf(a.x, b.x, fmaf(a.y, b.y, fmaf(a.z, b.z, a.w * b.w)));
}
__device__ __forceinline__ void bf2x(uint32 v, float& lo, float& hi) {
    union { uint32 u; float f; } a, b;
    a.u = v << 16; b.u = v & 0xffff0000u;
    lo = a.f; hi = b.f;
}
__device__ __forceinline__ float dot8bf(uint4 wv, const f4 hA, const f4 hB) {
    float w0, w1, w2, w3, w4, w5, w6, w7;
    bf2x(wv.x, w0, w1); bf2x(wv.y, w2, w3); bf2x(wv.z, w4, w5); bf2x(wv.w, w6, w7);
    float s = fmaf(w0, hA.x, w1 * hA.y);
    s = fmaf(w2, hA.z, s); s = fmaf(w3, hA.w, s);
    s = fmaf(w4, hB.x, s); s = fmaf(w5, hB.y, s);
    s = fmaf(w6, hB.z, s); s = fmaf(w7, hB.w, s);
    return s;
}
__device__ __forceinline__ ushort f2bf(float f) {
    union { float f; uint32 u; } a; a.f = f;
    uint32 r = a.u + 0x7fffu + ((a.u >> 16) & 1u);
    return (ushort)(r >> 16);
}

// ---- 4-batch act stage: f4 slot A0(kq,b) with pad (conflict-free) ----
#define A0(kq, b) ((kq) * 4 + ((kq) >> 3) + (b))
#define ST4_SZ 544  // f4 slots (2176 floats)
__device__ __forceinline__ void stage4(const float* __restrict__ src, float* __restrict__ st,
                                       int tid) {
    f4* d = (f4*)st;
    const f4* s = (const f4*)src;
    for (int idx = tid; idx < 512; idx += 256) {
        int b = idx >> 7, kq = idx & 127;
        d[A0(kq, b)] = s[idx];
    }
}

// ---- full-batch swizzled stage (attn/gi kernels) ----
__device__ __forceinline__ void stage_b32(const float* __restrict__ src, float* __restrict__ st,
                                          int tid, int nthr) {
    f4* d = (f4*)st;
    const f4* s = (const f4*)src;
    for (int idx = tid; idx < 4096; idx += nthr) {
        int b = idx >> 7, kq = idx & 127;
        d[kq * 32 + (b ^ (kq & 31))] = s[idx];
    }
}
__device__ __forceinline__ f4 ldb32(const float* __restrict__ st, int kq, int b) {
    return ((const f4*)st)[kq * 32 + (b ^ (kq & 31))];
}

// ---------------- merged fp32 -> bf16 convert for the 4 GRU weight mats ----------------
// sizes (f4 units): Wi0 393216, Wh0/Wi1/Wh1 196608 each -> 983040 total, 3840 blocks x 256
__global__ void cvt4_bf16_kernel(const float* __restrict__ s0, ushort* __restrict__ d0,
                                 const float* __restrict__ s1, ushort* __restrict__ d1,
                                 const float* __restrict__ s2, ushort* __restrict__ d2,
                                 const float* __restrict__ s3, ushort* __restrict__ d3) {
    int i = blockIdx.x * 256 + threadIdx.x;
    const float* s;
    ushort* d;
    int off;
    if (i < 393216) { s = s0; d = d0; off = i; }
    else if (i < 589824) { s = s1; d = d1; off = i - 393216; }
    else if (i < 786432) { s = s2; d = d2; off = i - 589824; }
    else { s = s3; d = d3; off = i - 786432; }
    f4 v = ((const f4*)s)[off];
    ushort4 o;
    o.x = f2bf(v.x); o.y = f2bf(v.y); o.z = f2bf(v.z); o.w = f2bf(v.w);
    ((ushort4*)d)[off] = o;
}

// ---------------- 32x32 tiled transpose (Wk only, fp32) ----------------
__global__ void transpose_kernel(const float* __restrict__ in, float* __restrict__ out,
                                 int R, int C, int ldin) {
    __shared__ float tile[32][33];
    int r0 = blockIdx.x * 32, c0 = blockIdx.y * 32;
    int tx = threadIdx.x & 31, ty = threadIdx.x >> 5;
#pragma unroll
    for (int k = 0; k < 4; ++k) {
        int r = r0 + ty + k * 8;
        tile[ty + k * 8][tx] = in[(size_t)r * ldin + c0 + tx];
    }
    __syncthreads();
#pragma unroll
    for (int k = 0; k < 4; ++k) {
        int c = c0 + ty + k * 8;
        out[(size_t)c * R + r0 + tx] = tile[tx][ty + k * 8];
    }
}

// ---------------- kpT[b][c][t] = sum_k enc[b*T+t][k] * WkT[k][c] ----------------
__global__ void __launch_bounds__(256) kproj_gemm_kernel(const float* __restrict__ A,
                                                         const float* __restrict__ Bt,
                                                         float* __restrict__ kpT) {
    __shared__ float As[64][68];
    __shared__ float Bs[64][64];
    int r0 = blockIdx.x * 64, c0 = blockIdx.y * 64;
    int tid = threadIdx.x;
    int tx = tid & 15, ty = tid >> 4;
    float acc[4][4] = {};
    for (int k0 = 0; k0 < 512; k0 += 64) {
#pragma unroll
        for (int i = 0; i < 4; ++i) {
            int row = i * 16 + ty, col = tx * 4;
            f4 av = *(const f4*)(A + (size_t)(r0 + row) * 512 + k0 + col);
            As[row][col] = av.x; As[row][col + 1] = av.y; As[row][col + 2] = av.z; As[row][col + 3] = av.w;
            f4 bv = *(const f4*)(Bt + (size_t)(k0 + row) * 512 + c0 + col);
            *(f4*)&Bs[row][col] = bv;
        }
        __syncthreads();
#pragma unroll 8
        for (int kk = 0; kk < 64; ++kk) {
            float a[4];
#pragma unroll
            for (int i = 0; i < 4; ++i) a[i] = As[ty * 4 + i][kk];
            f4 bv = *(const f4*)&Bs[kk][tx * 4];
#pragma unroll
            for (int i = 0; i < 4; ++i) {
                acc[i][0] += a[i] * bv.x; acc[i][1] += a[i] * bv.y;
                acc[i][2] += a[i] * bv.z; acc[i][3] += a[i] * bv.w;
            }
        }
        __syncthreads();
    }
#pragma unroll
    for (int i = 0; i < 4; ++i) {
        int r = r0 + ty * 4 + i;
        int b = r >> 7, t = r & 127;
#pragma unroll
        for (int j = 0; j < 4; ++j) {
            int c = c0 + tx * 4 + j;
            kpT[((size_t)b * H + c) * T + t] = acc[i][j];
        }
    }
}

// ---------------- init ----------------
__global__ void __launch_bounds__(512) init_kernel(const float* __restrict__ hidden,
                                                   const float* __restrict__ emb_W,
                                                   const float* __restrict__ emb_b,
                                                   float* __restrict__ h0, float* __restrict__ h1,
                                                   float* __restrict__ inp) {
    int b = blockIdx.x, tid = threadIdx.x;
    h0[b * H + tid] = hidden[b * H + tid];
    h1[b * H + tid] = hidden[BH + b * H + tid];
    if (b == 0) {
        const f4* row = (const f4*)(emb_W + (size_t)tid * ODIM);
        float acc = emb_b[tid];
#pragma unroll 8
        for (int o = 0; o < 64; ++o) { f4 v = row[o]; acc += v.x + v.y + v.z + v.w; }
        for (int bb = 0; bb < B; ++bb) inp[bb * E + tid] = acc;
    }
}

// ---------------- attn1: qproj (64 x 8j, all b) + lin(prev) (32 x 8o, all b) ----------------
__global__ void __launch_bounds__(256) attn1_kernel(
    int nb_q, const float* __restrict__ h1cur, const float* __restrict__ Wq,
    float* __restrict__ q, const float* __restrict__ last_W, const float* __restrict__ last_b,
    const float* __restrict__ target_step, const int* __restrict__ mask_step,
    float* __restrict__ f, float* __restrict__ out_step) {
    __shared__ float sh[16384];
    int tid = threadIdx.x;
    stage_b32(h1cur, sh, tid, 256);
    __syncthreads();
    if ((int)blockIdx.x < nb_q) {
        int jg = blockIdx.x * 8 + (tid & 7), b = tid >> 3;
        const f4* w = (const f4*)(Wq + (size_t)jg * H);
        float acc = 0.f;
#pragma unroll 8
        for (int kq = 0; kq < 128; ++kq) acc += dot4(w[kq], ldb32(sh, kq, b));
        q[b * H + jg] = acc;
    } else {
        int og = (blockIdx.x - nb_q) * 8 + (tid & 7), b = tid >> 3;
        const f4* w = (const f4*)(last_W + (size_t)og * H);
        float acc = 0.f;
#pragma unroll 8
        for (int kq = 0; kq < 128; ++kq) acc += dot4(w[kq], ldb32(sh, kq, b));
        float lin = acc + last_b[og];
        float ff = mask_step[b] ? target_step[b * ODIM + og] : lin;
        f[b * ODIM + og] = ff;
        out_step[b * ODIM + og] = ff;
    }
}

// ---------------- attn2: scores partials (256 blk) + emb(prev) (32 blk) ----------------
__global__ void __launch_bounds__(256) attn2_kernel(
    const float* __restrict__ q, const float* __restrict__ kpT, const float* __restrict__ wv,
    float* __restrict__ spart, const float* __restrict__ f, const float* __restrict__ emb_W,
    const float* __restrict__ emb_b, float* __restrict__ inp) {
    __shared__ float sm[8704];
    int tid = threadIdx.x;
    if ((int)blockIdx.x < 256) {
        int b = blockIdx.x >> 3, js = blockIdx.x & 7;
        float* qs = sm;
        float* ws_ = sm + 64;
        float* part = sm + 128;
        if (tid < 64) {
            qs[tid] = q[b * H + js * 64 + tid];
            ws_[tid] = wv[js * 64 + tid];
        }
        __syncthreads();
        int t = tid & 127, jh = tid >> 7;
        const float* kp = kpT + ((size_t)b * H + js * 64 + jh * 32) * T + t;
        float sa = 0.f;
#pragma unroll 8
        for (int jj = 0; jj < 32; ++jj) {
            int j = jh * 32 + jj;
            sa += tanh_fast(qs[j] + kp[(size_t)jj * T]) * ws_[j];
        }
        part[tid] = sa;
        __syncthreads();
        if (tid < 128) spart[((size_t)b * 8 + js) * T + tid] = part[tid] + part[128 + tid];
    } else {
        float* st = sm;
        {
            f4* d = (f4*)st;
            const f4* s = (const f4*)f;
            for (int idx = tid; idx < 2048; idx += 256) {
                int b = idx >> 6, oq = idx & 63;
                d[oq * 32 + (b ^ (oq & 31))] = s[idx];
            }
        }
        __syncthreads();
        int eg = (blockIdx.x - 256) * 16 + (tid & 15), bq = tid >> 4;
        const f4* w = (const f4*)(emb_W + (size_t)eg * ODIM);
        float a0 = 0.f, a1 = 0.f;
#pragma unroll 4
        for (int oq = 0; oq < 64; ++oq) {
            f4 wv_ = w[oq];
            a0 += dot4(wv_, ((const f4*)st)[oq * 32 + (bq ^ (oq & 31))]);
            a1 += dot4(wv_, ((const f4*)st)[oq * 32 + ((bq + 16) ^ (oq & 31))]);
        }
        float eb = emb_b[eg];
        inp[bq * E + eg] = a0 + eb;
        inp[(bq + 16) * E + eg] = a1 + eb;
    }
}

// ---------------- attn3: softmax + ctx (256 blk: 32b x 8cs) ----------------
__global__ void __launch_bounds__(256) attn3_kernel(
    const float* __restrict__ spart, const float* __restrict__ enc,
    float* __restrict__ ctx, float* __restrict__ attn_out) {
    __shared__ float sw[T];
    __shared__ float red[4];
    __shared__ float part[256];
    int tid = threadIdx.x;
    int b = blockIdx.x >> 3, cs = blockIdx.x & 7;
    float sv = 0.f;
    if (tid < 128) {
        const float* sp = spart + (size_t)b * 8 * T + tid;
#pragma unroll
        for (int js = 0; js < 8; ++js) sv += sp[js * T];
        float m = sv;
        for (int off = 32; off; off >>= 1) m = fmaxf(m, __shfl_xor(m, off));
        if ((tid & 63) == 0) red[tid >> 6] = m;
    }
    __syncthreads();
    if (tid < 128) {
        float M = fmaxf(red[0], red[1]);
        float e = __expf(sv - M);
        sw[tid] = e;
        float s = e;
        for (int off = 32; off; off >>= 1) s += __shfl_xor(s, off);
        if ((tid & 63) == 0) red[2 + (tid >> 6)] = s;
    }
    __syncthreads();
    if (tid < 128) {
        float w = sw[tid] / (red[2] + red[3]);
        sw[tid] = w;
        if (cs == 0) attn_out[(size_t)b * T + tid] = w;
    }
    __syncthreads();
    int c = tid & 63, tq = tid >> 6;
    int cg = cs * 64 + c;
    const float* ep = enc + ((size_t)b * T + tq * 32) * H + cg;
    float acc = 0.f;
#pragma unroll 8
    for (int t2 = 0; t2 < 32; ++t2) acc += sw[tq * 32 + t2] * ep[(size_t)t2 * H];
    part[tid] = acc;
    __syncthreads();
    if (tid < 64) ctx[(size_t)b * H + cg] = part[tid] + part[64 + tid] + part[128 + tid] + part[192 + tid];
}

// ---------------- gi (bf16 W row-major): 96 blk gi_ctx (+bi0) | 96 blk gi_emb[i] ----------------
__global__ void __launch_bounds__(256) gi_kernel(
    const float* __restrict__ ctx, const float* __restrict__ inp,
    const ushort* __restrict__ Wi0bf, const float* __restrict__ bi0,
    float* __restrict__ gi_ctx, float* __restrict__ gi_emb_i) {
    __shared__ float sh[16384];
    int tid = threadIdx.x;
    bool isC = (int)blockIdx.x < 96;
    int lb = isC ? blockIdx.x : blockIdx.x - 96;
    stage_b32(isC ? ctx : inp, sh, tid, 256);
    __syncthreads();
    int cg = lb * 16 + (tid & 15), bq = tid >> 4;
    const uint4* w = (const uint4*)(Wi0bf + (size_t)cg * 1024 + (isC ? 0 : 512));
    float a0 = 0.f, a1 = 0.f;
#pragma unroll 4
    for (int it = 0; it < 64; ++it) {
        uint4 wv_ = w[it];
        f4 hA0 = ldb32(sh, it * 2, bq), hB0 = ldb32(sh, it * 2 + 1, bq);
        f4 hA1 = ldb32(sh, it * 2, bq + 16), hB1 = ldb32(sh, it * 2 + 1, bq + 16);
        a0 += dot8bf(wv_, hA0, hB0);
        a1 += dot8bf(wv_, hA1, hB1);
    }
    float bias = isC ? bi0[cg] : 0.f;
    float* dst = isC ? gi_ctx : gi_emb_i;
    dst[(size_t)bq * G3 + cg] = a0 + bias;
    dst[(size_t)(bq + 16) * G3 + cg] = a1 + bias;
}

// ---------------- fused dual GRU cell: 4x dup (8 batches/block), k-contig bf16 uint4 ----------------
// l0: blocks [0,nb0=256): jc=bid&63 (8 j), bg=bid>>6 (8 b). threads: j8 x ks16 x bh2
// l1: blocks [nb0,+256): same geometry; threads: j8 x ks8 x bh2 x m2
__global__ void __launch_bounds__(256) cell_kernel(
    int nb0, const float* __restrict__ h0_src, float* __restrict__ h0_dst,
    const float* __restrict__ h1_src, float* __restrict__ h1_dst,
    const float* __restrict__ gi_emb_t, const float* __restrict__ gi_ctx,
    const ushort* __restrict__ Wh0bf, const float* __restrict__ bh0,
    const ushort* __restrict__ Wi1bf, const float* __restrict__ bi1,
    const ushort* __restrict__ Wh1bf, const float* __restrict__ bh1) {
    __shared__ __align__(16) float sh[8704];  // 34.8 KB
    int tid = threadIdx.x;
    if ((int)blockIdx.x < nb0) {
        int jc = blockIdx.x & 63, bg = blockIdx.x >> 6;
        int j0 = jc * 8, b0 = bg * 8;
        float* stA = sh;          // batches b0..b0+3
        float* stB = sh + 2176;   // batches b0+4..b0+7
        stage4(h0_src + (size_t)b0 * H, stA, tid);
        stage4(h0_src + (size_t)(b0 + 4) * H, stB, tid);
        __syncthreads();
        int j = tid & 7, ks = (tid >> 3) & 15, bh = tid >> 7, jg = j0 + j;
        const float* stm = bh ? stB : stA;
        const uint4* w0 = (const uint4*)(Wh0bf + (size_t)jg * 512) + ks * 4;
        const uint4* w1 = (const uint4*)(Wh0bf + (size_t)(512 + jg) * 512) + ks * 4;
        const uint4* w2 = (const uint4*)(Wh0bf + (size_t)(1024 + jg) * 512) + ks * 4;
        float a0[4] = {}, a1[4] = {}, a2[4] = {};
#pragma unroll
        for (int c = 0; c < 4; ++c) {
            uint4 u0 = w0[c], u1 = w1[c], u2 = w2[c];
            int kq = ks * 8 + c * 2;
#pragma unroll
            for (int b = 0; b < 4; ++b) {
                f4 hA = ((const f4*)stm)[A0(kq, b)];
                f4 hB = ((const f4*)stm)[A0(kq + 1, b)];
                a0[b] += dot8bf(u0, hA, hB);
                a1[b] += dot8bf(u1, hA, hB);
                a2[b] += dot8bf(u2, hA, hB);
            }
        }
        float* part = sh + 4352;  // 3328 floats, no alias with stages
        {
            float* pr = part + (size_t)tid * 13;
#pragma unroll
            for (int b = 0; b < 4; ++b) { pr[b] = a0[b]; pr[4 + b] = a1[b]; pr[8 + b] = a2[b]; }
        }
        __syncthreads();
        if (tid < 64) {
            int fj = tid & 7, fb = tid >> 3;
            int bh2 = fb >> 2, fbi = fb & 3;
            int jg2 = j0 + fj, bg2 = b0 + fb;
            float s0 = 0.f, s1 = 0.f, s2 = 0.f;
#pragma unroll
            for (int k2 = 0; k2 < 16; ++k2) {
                const float* p = part + (size_t)(bh2 * 128 + k2 * 8 + fj) * 13;
                s0 += p[fbi]; s1 += p[4 + fbi]; s2 += p[8 + fbi];
            }
            const float* gc = gi_ctx + (size_t)bg2 * G3;
            const float* ge = gi_emb_t + (size_t)bg2 * G3;
            float r_ = sigmoidf_(gc[jg2] + ge[jg2] + s0 + bh0[jg2]);
            float z_ = sigmoidf_(gc[H + jg2] + ge[H + jg2] + s1 + bh0[H + jg2]);
            float n_ = tanh_fast(gc[2 * H + jg2] + ge[2 * H + jg2] + r_ * (s2 + bh0[2 * H + jg2]));
            const float* stm2 = (fb >= 4) ? stB : stA;
            f4 hp = ((const f4*)stm2)[A0(jg2 >> 2, fb & 3)];
            float hprev = ((const float*)&hp)[jg2 & 3];
            h0_dst[(size_t)bg2 * H + jg2] = (1.f - z_) * n_ + z_ * hprev;
        }
    } else {
        int lb = blockIdx.x - nb0;
        int jc = lb & 63, bg = lb >> 6;
        int j0 = jc * 8, b0 = bg * 8;
        float* stX0 = sh;           // x, b0..b0+3
        float* stX1 = sh + 2176;    // x, b0+4..b0+7
        float* stH0 = sh + 4352;    // h, b0..b0+3
        float* stH1 = sh + 6528;    // h, b0+4..b0+7
        stage4(h0_src + (size_t)b0 * H, stX0, tid);
        stage4(h0_src + (size_t)(b0 + 4) * H, stX1, tid);
        stage4(h1_src + (size_t)b0 * H, stH0, tid);
        stage4(h1_src + (size_t)(b0 + 4) * H, stH1, tid);
        __syncthreads();
        int j = tid & 7, ks = (tid >> 3) & 7, bh = (tid >> 6) & 1, m = tid >> 7, jg = j0 + j;
        const float* stm = m ? (bh ? stH1 : stH0) : (bh ? stX1 : stX0);
        const ushort* Wm = m ? Wh1bf : Wi1bf;
        const uint4* w0 = (const uint4*)(Wm + (size_t)jg * 512) + ks * 8;
        const uint4* w1 = (const uint4*)(Wm + (size_t)(512 + jg) * 512) + ks * 8;
        const uint4* w2 = (const uint4*)(Wm + (size_t)(1024 + jg) * 512) + ks * 8;
        float a0[4] = {}, a1[4] = {}, a2[4] = {};
#pragma unroll
        for (int c = 0; c < 8; ++c) {
            uint4 u0 = w0[c], u1 = w1[c], u2 = w2[c];
            int kq = ks * 16 + c * 2;
#pragma unroll
            for (int b = 0; b < 4; ++b) {
                f4 hA = ((const f4*)stm)[A0(kq, b)];
                f4 hB = ((const f4*)stm)[A0(kq + 1, b)];
                a0[b] += dot8bf(u0, hA, hB);
                a1[b] += dot8bf(u1, hA, hB);
                a2[b] += dot8bf(u2, hA, hB);
            }
        }
        __syncthreads();  // all x/h reads done before aliasing partials onto x-stage
        float* part = sh;  // 3328 floats alias stX0/stX1 (dead); stH untouched
        {
            float* pr = part + (size_t)tid * 13;
#pragma unroll
            for (int b = 0; b < 4; ++b) { pr[b] = a0[b]; pr[4 + b] = a1[b]; pr[8 + b] = a2[b]; }
        }
        __syncthreads();
        if (tid < 64) {
            int fj = tid & 7, fb = tid >> 3;
            int bh2 = fb >> 2, fbi = fb & 3;
            int jg2 = j0 + fj, bg2 = b0 + fb;
            float i0 = 0.f, i1 = 0.f, i2 = 0.f, g0 = 0.f, g1 = 0.f, g2 = 0.f;
#pragma unroll
            for (int k2 = 0; k2 < 8; ++k2) {
                const float* pi = part + (size_t)(bh2 * 64 + k2 * 8 + fj) * 13;
                const float* ph = part + (size_t)(128 + bh2 * 64 + k2 * 8 + fj) * 13;
                i0 += pi[fbi]; i1 += pi[4 + fbi]; i2 += pi[8 + fbi];
                g0 += ph[fbi]; g1 += ph[4 + fbi]; g2 += ph[8 + fbi];
            }
            float r_ = sigmoidf_(i0 + bi1[jg2] + g0 + bh1[jg2]);
            float z_ = sigmoidf_(i1 + bi1[H + jg2] + g1 + bh1[H + jg2]);
            float n_ = tanh_fast(i2 + bi1[2 * H + jg2] + r_ * (g2 + bh1[2 * H + jg2]));
            const float* stm2 = (fb >= 4) ? stH1 : stH0;
            f4 hp = ((const f4*)stm2)[A0(jg2 >> 2, fb & 3)];
            float hprev = ((const float*)&hp)[jg2 & 3];
            h1_dst[(size_t)bg2 * H + jg2] = (1.f - z_) * n_ + z_ * hprev;
        }
    }
}

__global__ void copy_hidden_kernel(const float* __restrict__ h0, const float* __restrict__ h1,
                                   float* __restrict__ dst) {
    int i = blockIdx.x * 256 + threadIdx.x;
    dst[i] = h0[i];
    dst[BH + i] = h1[i];
}

extern "C" void kernel_launch(void* const* d_in, const int* in_sizes, int n_in,
                              void* d_out_v, int out_size, void* d_ws, size_t ws_size,
                              hipStream_t stream) {
    const float* enc = (const float*)d_in[0];
    const float* hidden = (const float*)d_in[1];
    const float* target = (const float*)d_in[2];
    const float* Wq = (const float*)d_in[3];
    const float* Wk = (const float*)d_in[4];
    const float* wv = (const float*)d_in[5];
    const float* emb_W = (const float*)d_in[6];
    const float* emb_b = (const float*)d_in[7];
    const float* Wi0 = (const float*)d_in[8];
    const float* Wh0 = (const float*)d_in[9];
    const float* bi0 = (const float*)d_in[10];
    const float* bh0 = (const float*)d_in[11];
    const float* Wi1 = (const float*)d_in[12];
    const float* Wh1 = (const float*)d_in[13];
    const float* bi1 = (const float*)d_in[14];
    const float* bh1 = (const float*)d_in[15];
    const float* last_W = (const float*)d_in[16];
    const float* last_b = (const float*)d_in[17];
    const int* tmask = (const int*)d_in[18];

    float* out = (float*)d_out_v;
    float* out_hidden = out + (size_t)STEPS * B * ODIM;
    float* out_attn = out_hidden + (size_t)2 * BH;

    float* ws = (float*)d_ws;
    float* kpT = ws;                      // 2,097,152
    float* WkT = kpT + 2097152;           // 262,144
    float* gi_emb = WkT + 262144;         // 786,432
    float* gi_ctx = gi_emb + 786432;      // 49,152
    float* h0buf = gi_ctx + 49152;        // 32,768 (2x)
    float* h1buf = h0buf + 32768;         // 32,768 (2x)
    float* qbuf = h1buf + 32768;          // 16,384
    float* ctxbuf = qbuf + 16384;         // 16,384
    float* fbuf = ctxbuf + 16384;         // 8,192
    float* inpbuf = fbuf + 8192;          // 16,384
    float* spart = inpbuf + 16384;        // 32,768
    ushort* Wi0bf = (ushort*)(spart + 32768);  // 1,572,864 ushorts
    ushort* Wh0bf = Wi0bf + 1572864;           // 786,432
    ushort* Wi1bf = Wh0bf + 786432;            // 786,432
    ushort* Wh1bf = Wi1bf + 786432;            // 786,432

    cvt4_bf16_kernel<<<3840, 256, 0, stream>>>(Wi0, Wi0bf, Wh0, Wh0bf, Wi1, Wi1bf, Wh1, Wh1bf);
    transpose_kernel<<<dim3(16, 16), 256, 0, stream>>>(Wk, WkT, 512, 512, 512);
    kproj_gemm_kernel<<<dim3(64, 8), 256, 0, stream>>>(enc, WkT, kpT);
    init_kernel<<<B, 512, 0, stream>>>(hidden, emb_W, emb_b, h0buf, h1buf, inpbuf);

    int p0 = 0, p1 = 0;
    for (int i = 0; i < STEPS; ++i) {
        int im1 = (i > 0) ? i - 1 : 0;
        const float* h1cur = h1buf + (size_t)p1 * BH;
        attn1_kernel<<<(i > 0) ? 96 : 64, 256, 0, stream>>>(
            64, h1cur, Wq, qbuf, last_W, last_b, target + (size_t)im1 * B * ODIM,
            tmask + im1 * B, fbuf, out + (size_t)im1 * B * ODIM);
        attn2_kernel<<<(i > 0) ? 288 : 256, 256, 0, stream>>>(qbuf, kpT, wv, spart, fbuf,
                                                              emb_W, emb_b, inpbuf);
        attn3_kernel<<<256, 256, 0, stream>>>(spart, enc, ctxbuf, out_attn + (size_t)i * B * T);
        gi_kernel<<<192, 256, 0, stream>>>(ctxbuf, inpbuf, Wi0bf, bi0, gi_ctx,
                                           gi_emb + (size_t)i * B * G3);
        for (int t = 0; t <= i + 1; ++t) {
            int nb0 = (t <= i) ? 256 : 0;
            int nb1 = (t >= 1) ? 256 : 0;
            int tge = (t <= i) ? t : 0;
            cell_kernel<<<nb0 + nb1, 256, 0, stream>>>(
                nb0, h0buf + (size_t)p0 * BH, h0buf + (size_t)(p0 ^ 1) * BH,
                h1buf + (size_t)p1 * BH, h1buf + (size_t)(p1 ^ 1) * BH,
                gi_emb + (size_t)tge * B * G3, gi_ctx, Wh0bf, bh0, Wi1bf, bi1, Wh1bf, bh1);
            if (nb0) p0 ^= 1;
            if (nb1) p1 ^= 1;
        }
    }
    // final lin (step 15)
    attn1_kernel<<<32, 256, 0, stream>>>(0, h1buf + (size_t)p1 * BH, Wq, qbuf, last_W, last_b,
                                         target + (size_t)15 * B * ODIM, tmask + 15 * B, fbuf,
                                         out + (size_t)15 * B * ODIM);
    copy_hidden_kernel<<<64, 256, 0, stream>>>(h0buf + (size_t)p0 * BH, h1buf + (size_t)p1 * BH,
                                               out_hidden);
}

// Round 15
// 2495.595 us; speedup vs baseline: 5.1036x; 2.3964x over previous
//
#include <hip/hip_runtime.h>
#include <math.h>

#define B 32
#define T 128
#define H 512
#define E 512
#define ODIM 256
#define STEPS 16
#define G3 1536
#define BH (B * H)

typedef float4 f4;
typedef unsigned int uint32;
typedef unsigned short ushort;

__device__ __forceinline__ float sigmoidf_(float x) { return 1.0f / (1.0f + __expf(-x)); }
__device__ __forceinline__ float tanh_fast(float x) {
    float t = __expf(-2.0f * fabsf(x));
    float r = (1.0f - t) / (1.0f + t);
    return __builtin_copysignf(r, x);
}
__device__ __forceinline__ float dot4(const f4 a, const f4 b) {
    return fmaf(a.x, b.x, fmaf(a.y, b.y, fmaf(a.z, b.z, a.w * b.w)));
}
__device__ __forceinline__ void bf2x(uint32 v, float& lo, float& hi) {
    union { uint32 u; float f; } a, b;
    a.u = v << 16; b.u = v & 0xffff0000u;
    lo = a.f; hi = b.f;
}
__device__ __forceinline__ float dot8bf(uint4 wv, const f4 hA, const f4 hB) {
    float w0, w1, w2, w3, w4, w5, w6, w7;
    bf2x(wv.x, w0, w1); bf2x(wv.y, w2, w3); bf2x(wv.z, w4, w5); bf2x(wv.w, w6, w7);
    float s = fmaf(w0, hA.x, w1 * hA.y);
    s = fmaf(w2, hA.z, s); s = fmaf(w3, hA.w, s);
    s = fmaf(w4, hB.x, s); s = fmaf(w5, hB.y, s);
    s = fmaf(w6, hB.z, s); s = fmaf(w7, hB.w, s);
    return s;
}
__device__ __forceinline__ ushort f2bf(float f) {
    union { float f; uint32 u; } a; a.f = f;
    uint32 r = a.u + 0x7fffu + ((a.u >> 16) & 1u);
    return (ushort)(r >> 16);
}

// ---- 4-batch act stage: f4 slot A0(kq,b) = kq*4 + (kq>>3) + b  (pad breaks 32-word aliasing) ----
#define A0(kq, b) ((kq) * 4 + ((kq) >> 3) + (b))
#define ST4_SZ 544  // > 127*4+15+3
__device__ __forceinline__ void stage4(const float* __restrict__ src, float* __restrict__ st,
                                       int tid) {
    f4* d = (f4*)st;
    const f4* s = (const f4*)src;
    for (int idx = tid; idx < 512; idx += 256) {
        int b = idx >> 7, kq = idx & 127;
        d[A0(kq, b)] = s[idx];
    }
}

// ---- full-batch swizzled stage (attn/gi kernels) ----
__device__ __forceinline__ void stage_b32(const float* __restrict__ src, float* __restrict__ st,
                                          int tid, int nthr) {
    f4* d = (f4*)st;
    const f4* s = (const f4*)src;
    for (int idx = tid; idx < 4096; idx += nthr) {
        int b = idx >> 7, kq = idx & 127;
        d[kq * 32 + (b ^ (kq & 31))] = s[idx];
    }
}
__device__ __forceinline__ f4 ldb32(const float* __restrict__ st, int kq, int b) {
    return ((const f4*)st)[kq * 32 + (b ^ (kq & 31))];
}

// ---------------- merged fp32 -> bf16 convert for the 4 GRU weight mats ----------------
__global__ void cvt4_bf16_kernel(const float* __restrict__ s0, ushort* __restrict__ d0,
                                 const float* __restrict__ s1, ushort* __restrict__ d1,
                                 const float* __restrict__ s2, ushort* __restrict__ d2,
                                 const float* __restrict__ s3, ushort* __restrict__ d3) {
    int i = blockIdx.x * 256 + threadIdx.x;
    const float* s;
    ushort* d;
    int off;
    if (i < 393216) { s = s0; d = d0; off = i; }
    else if (i < 589824) { s = s1; d = d1; off = i - 393216; }
    else if (i < 786432) { s = s2; d = d2; off = i - 589824; }
    else { s = s3; d = d3; off = i - 786432; }
    f4 v = ((const f4*)s)[off];
    ushort4 o;
    o.x = f2bf(v.x); o.y = f2bf(v.y); o.z = f2bf(v.z); o.w = f2bf(v.w);
    ((ushort4*)d)[off] = o;
}

// ---------------- 32x32 tiled transpose (Wk only, fp32) ----------------
__global__ void transpose_kernel(const float* __restrict__ in, float* __restrict__ out,
                                 int R, int C, int ldin) {
    __shared__ float tile[32][33];
    int r0 = blockIdx.x * 32, c0 = blockIdx.y * 32;
    int tx = threadIdx.x & 31, ty = threadIdx.x >> 5;
#pragma unroll
    for (int k = 0; k < 4; ++k) {
        int r = r0 + ty + k * 8;
        tile[ty + k * 8][tx] = in[(size_t)r * ldin + c0 + tx];
    }
    __syncthreads();
#pragma unroll
    for (int k = 0; k < 4; ++k) {
        int c = c0 + ty + k * 8;
        out[(size_t)c * R + r0 + tx] = tile[tx][ty + k * 8];
    }
}

// ---------------- kpT[b][c][t] = sum_k enc[b*T+t][k] * WkT[k][c] ----------------
__global__ void __launch_bounds__(256) kproj_gemm_kernel(const float* __restrict__ A,
                                                         const float* __restrict__ Bt,
                                                         float* __restrict__ kpT) {
    __shared__ float As[64][68];
    __shared__ float Bs[64][64];
    int r0 = blockIdx.x * 64, c0 = blockIdx.y * 64;
    int tid = threadIdx.x;
    int tx = tid & 15, ty = tid >> 4;
    float acc[4][4] = {};
    for (int k0 = 0; k0 < 512; k0 += 64) {
#pragma unroll
        for (int i = 0; i < 4; ++i) {
            int row = i * 16 + ty, col = tx * 4;
            f4 av = *(const f4*)(A + (size_t)(r0 + row) * 512 + k0 + col);
            As[row][col] = av.x; As[row][col + 1] = av.y; As[row][col + 2] = av.z; As[row][col + 3] = av.w;
            f4 bv = *(const f4*)(Bt + (size_t)(k0 + row) * 512 + c0 + col);
            *(f4*)&Bs[row][col] = bv;
        }
        __syncthreads();
#pragma unroll 8
        for (int kk = 0; kk < 64; ++kk) {
            float a[4];
#pragma unroll
            for (int i = 0; i < 4; ++i) a[i] = As[ty * 4 + i][kk];
            f4 bv = *(const f4*)&Bs[kk][tx * 4];
#pragma unroll
            for (int i = 0; i < 4; ++i) {
                acc[i][0] += a[i] * bv.x; acc[i][1] += a[i] * bv.y;
                acc[i][2] += a[i] * bv.z; acc[i][3] += a[i] * bv.w;
            }
        }
        __syncthreads();
    }
#pragma unroll
    for (int i = 0; i < 4; ++i) {
        int r = r0 + ty * 4 + i;
        int b = r >> 7, t = r & 127;
#pragma unroll
        for (int j = 0; j < 4; ++j) {
            int c = c0 + tx * 4 + j;
            kpT[((size_t)b * H + c) * T + t] = acc[i][j];
        }
    }
}

// ---------------- init ----------------
__global__ void __launch_bounds__(512) init_kernel(const float* __restrict__ hidden,
                                                   const float* __restrict__ emb_W,
                                                   const float* __restrict__ emb_b,
                                                   float* __restrict__ h0, float* __restrict__ h1,
                                                   float* __restrict__ inp) {
    int b = blockIdx.x, tid = threadIdx.x;
    h0[b * H + tid] = hidden[b * H + tid];
    h1[b * H + tid] = hidden[BH + b * H + tid];
    if (b == 0) {
        const f4* row = (const f4*)(emb_W + (size_t)tid * ODIM);
        float acc = emb_b[tid];
#pragma unroll 8
        for (int o = 0; o < 64; ++o) { f4 v = row[o]; acc += v.x + v.y + v.z + v.w; }
        for (int bb = 0; bb < B; ++bb) inp[bb * E + tid] = acc;
    }
}

// ---------------- attn1: qproj (64 x 8j, all b) + lin(prev) (32 x 8o, all b) ----------------
__global__ void __launch_bounds__(256) attn1_kernel(
    int nb_q, const float* __restrict__ h1cur, const float* __restrict__ Wq,
    float* __restrict__ q, const float* __restrict__ last_W, const float* __restrict__ last_b,
    const float* __restrict__ target_step, const int* __restrict__ mask_step,
    float* __restrict__ f, float* __restrict__ out_step) {
    __shared__ float sh[16384];
    int tid = threadIdx.x;
    stage_b32(h1cur, sh, tid, 256);
    __syncthreads();
    if ((int)blockIdx.x < nb_q) {
        int jg = blockIdx.x * 8 + (tid & 7), b = tid >> 3;
        const f4* w = (const f4*)(Wq + (size_t)jg * H);
        float acc = 0.f;
#pragma unroll 8
        for (int kq = 0; kq < 128; ++kq) acc += dot4(w[kq], ldb32(sh, kq, b));
        q[b * H + jg] = acc;
    } else {
        int og = (blockIdx.x - nb_q) * 8 + (tid & 7), b = tid >> 3;
        const f4* w = (const f4*)(last_W + (size_t)og * H);
        float acc = 0.f;
#pragma unroll 8
        for (int kq = 0; kq < 128; ++kq) acc += dot4(w[kq], ldb32(sh, kq, b));
        float lin = acc + last_b[og];
        float ff = mask_step[b] ? target_step[b * ODIM + og] : lin;
        f[b * ODIM + og] = ff;
        out_step[b * ODIM + og] = ff;
    }
}

// ---------------- attn2: scores partials (256 blk) + emb(prev) (32 blk) ----------------
__global__ void __launch_bounds__(256) attn2_kernel(
    const float* __restrict__ q, const float* __restrict__ kpT, const float* __restrict__ wv,
    float* __restrict__ spart, const float* __restrict__ f, const float* __restrict__ emb_W,
    const float* __restrict__ emb_b, float* __restrict__ inp) {
    __shared__ float sm[8704];
    int tid = threadIdx.x;
    if ((int)blockIdx.x < 256) {
        int b = blockIdx.x >> 3, js = blockIdx.x & 7;
        float* qs = sm;
        float* ws_ = sm + 64;
        float* part = sm + 128;
        if (tid < 64) {
            qs[tid] = q[b * H + js * 64 + tid];
            ws_[tid] = wv[js * 64 + tid];
        }
        __syncthreads();
        int t = tid & 127, jh = tid >> 7;
        const float* kp = kpT + ((size_t)b * H + js * 64 + jh * 32) * T + t;
        float sa = 0.f;
#pragma unroll 8
        for (int jj = 0; jj < 32; ++jj) {
            int j = jh * 32 + jj;
            sa += tanh_fast(qs[j] + kp[(size_t)jj * T]) * ws_[j];
        }
        part[tid] = sa;
        __syncthreads();
        if (tid < 128) spart[((size_t)b * 8 + js) * T + tid] = part[tid] + part[128 + tid];
    } else {
        float* st = sm;
        {
            f4* d = (f4*)st;
            const f4* s = (const f4*)f;
            for (int idx = tid; idx < 2048; idx += 256) {
                int b = idx >> 6, oq = idx & 63;
                d[oq * 32 + (b ^ (oq & 31))] = s[idx];
            }
        }
        __syncthreads();
        int eg = (blockIdx.x - 256) * 16 + (tid & 15), bq = tid >> 4;
        const f4* w = (const f4*)(emb_W + (size_t)eg * ODIM);
        float a0 = 0.f, a1 = 0.f;
#pragma unroll 4
        for (int oq = 0; oq < 64; ++oq) {
            f4 wv_ = w[oq];
            a0 += dot4(wv_, ((const f4*)st)[oq * 32 + (bq ^ (oq & 31))]);
            a1 += dot4(wv_, ((const f4*)st)[oq * 32 + ((bq + 16) ^ (oq & 31))]);
        }
        float eb = emb_b[eg];
        inp[bq * E + eg] = a0 + eb;
        inp[(bq + 16) * E + eg] = a1 + eb;
    }
}

// ---------------- attn3: softmax + ctx (256 blk: 32b x 8cs) ----------------
__global__ void __launch_bounds__(256) attn3_kernel(
    const float* __restrict__ spart, const float* __restrict__ enc,
    float* __restrict__ ctx, float* __restrict__ attn_out) {
    __shared__ float sw[T];
    __shared__ float red[4];
    __shared__ float part[256];
    int tid = threadIdx.x;
    int b = blockIdx.x >> 3, cs = blockIdx.x & 7;
    float sv = 0.f;
    if (tid < 128) {
        const float* sp = spart + (size_t)b * 8 * T + tid;
#pragma unroll
        for (int js = 0; js < 8; ++js) sv += sp[js * T];
        float m = sv;
        for (int off = 32; off; off >>= 1) m = fmaxf(m, __shfl_xor(m, off));
        if ((tid & 63) == 0) red[tid >> 6] = m;
    }
    __syncthreads();
    if (tid < 128) {
        float M = fmaxf(red[0], red[1]);
        float e = __expf(sv - M);
        sw[tid] = e;
        float s = e;
        for (int off = 32; off; off >>= 1) s += __shfl_xor(s, off);
        if ((tid & 63) == 0) red[2 + (tid >> 6)] = s;
    }
    __syncthreads();
    if (tid < 128) {
        float w = sw[tid] / (red[2] + red[3]);
        sw[tid] = w;
        if (cs == 0) attn_out[(size_t)b * T + tid] = w;
    }
    __syncthreads();
    int c = tid & 63, tq = tid >> 6;
    int cg = cs * 64 + c;
    const float* ep = enc + ((size_t)b * T + tq * 32) * H + cg;
    float acc = 0.f;
#pragma unroll 8
    for (int t2 = 0; t2 < 32; ++t2) acc += sw[tq * 32 + t2] * ep[(size_t)t2 * H];
    part[tid] = acc;
    __syncthreads();
    if (tid < 64) ctx[(size_t)b * H + cg] = part[tid] + part[64 + tid] + part[128 + tid] + part[192 + tid];
}

// ---------------- gi (bf16 W row-major): 96 blk gi_ctx (+bi0) | 96 blk gi_emb[i] ----------------
__global__ void __launch_bounds__(256) gi_kernel(
    const float* __restrict__ ctx, const float* __restrict__ inp,
    const ushort* __restrict__ Wi0bf, const float* __restrict__ bi0,
    float* __restrict__ gi_ctx, float* __restrict__ gi_emb_i) {
    __shared__ float sh[16384];
    int tid = threadIdx.x;
    bool isC = (int)blockIdx.x < 96;
    int lb = isC ? blockIdx.x : blockIdx.x - 96;
    stage_b32(isC ? ctx : inp, sh, tid, 256);
    __syncthreads();
    int cg = lb * 16 + (tid & 15), bq = tid >> 4;
    const uint4* w = (const uint4*)(Wi0bf + (size_t)cg * 1024 + (isC ? 0 : 512));
    float a0 = 0.f, a1 = 0.f;
#pragma unroll 4
    for (int it = 0; it < 64; ++it) {
        uint4 wv_ = w[it];
        f4 hA0 = ldb32(sh, it * 2, bq), hB0 = ldb32(sh, it * 2 + 1, bq);
        f4 hA1 = ldb32(sh, it * 2, bq + 16), hB1 = ldb32(sh, it * 2 + 1, bq + 16);
        a0 += dot8bf(wv_, hA0, hB0);
        a1 += dot8bf(wv_, hA1, hB1);
    }
    float bias = isC ? bi0[cg] : 0.f;
    float* dst = isC ? gi_ctx : gi_emb_i;
    dst[(size_t)bq * G3 + cg] = a0 + bias;
    dst[(size_t)(bq + 16) * G3 + cg] = a1 + bias;
}

// ---------------- fused dual GRU cell: row-major bf16, k-contiguous uint4, k-split reduce ----------------
// l0: blocks [0,nb0=256): jc=bid&31 (16 j), bg=bid>>5 (4 b). threads: j=tid&15, ks=tid>>4 (16 x 32k)
// l1: blocks [nb0,+256): same geometry; threads: j=tid&15, ks=(tid>>4)&7 (8 x 64k), m=tid>>7
__global__ void __launch_bounds__(256) cell_kernel(
    int nb0, const float* __restrict__ h0_src, float* __restrict__ h0_dst,
    const float* __restrict__ h1_src, float* __restrict__ h1_dst,
    const float* __restrict__ gi_emb_t, const float* __restrict__ gi_ctx,
    const ushort* __restrict__ Wh0bf, const float* __restrict__ bh0,
    const ushort* __restrict__ Wi1bf, const float* __restrict__ bi1,
    const ushort* __restrict__ Wh1bf, const float* __restrict__ bh1) {
    __shared__ __align__(16) float sh[7936];  // 31.75 KB max (l1)
    int tid = threadIdx.x;
    if ((int)blockIdx.x < nb0) {
        int jc = blockIdx.x & 31, bg = blockIdx.x >> 5;
        int j0 = jc * 16, b0 = bg * 4;
        stage4(h0_src + (size_t)b0 * H, sh, tid);
        __syncthreads();
        int j = tid & 15, ks = tid >> 4, jg = j0 + j;
        const uint4* w0 = (const uint4*)(Wh0bf + (size_t)jg * 512) + ks * 4;
        const uint4* w1 = (const uint4*)(Wh0bf + (size_t)(512 + jg) * 512) + ks * 4;
        const uint4* w2 = (const uint4*)(Wh0bf + (size_t)(1024 + jg) * 512) + ks * 4;
        float a0[4] = {}, a1[4] = {}, a2[4] = {};
#pragma unroll
        for (int c = 0; c < 4; ++c) {
            uint4 u0 = w0[c], u1 = w1[c], u2 = w2[c];
            int kq = ks * 8 + c * 2;
#pragma unroll
            for (int b = 0; b < 4; ++b) {
                f4 hA = ((const f4*)sh)[A0(kq, b)];
                f4 hB = ((const f4*)sh)[A0(kq + 1, b)];
                a0[b] += dot8bf(u0, hA, hB);
                a1[b] += dot8bf(u1, hA, hB);
                a2[b] += dot8bf(u2, hA, hB);
            }
        }
        float* part = sh + ST4_SZ * 4;  // 2176 floats in
        {
            float* p = part + (size_t)tid * 13;
#pragma unroll
            for (int b = 0; b < 4; ++b) { p[b] = a0[b]; p[4 + b] = a1[b]; p[8 + b] = a2[b]; }
        }
        __syncthreads();
        if (tid < 64) {
            int fj = tid & 15, fb = tid >> 4;
            int jg2 = j0 + fj, bg2 = b0 + fb;
            float s0 = 0.f, s1 = 0.f, s2 = 0.f;
#pragma unroll
            for (int k2 = 0; k2 < 16; ++k2) {
                const float* p = part + (size_t)(k2 * 16 + fj) * 13;
                s0 += p[fb]; s1 += p[4 + fb]; s2 += p[8 + fb];
            }
            const float* gc = gi_ctx + (size_t)bg2 * G3;
            const float* ge = gi_emb_t + (size_t)bg2 * G3;
            float r_ = sigmoidf_(gc[jg2] + ge[jg2] + s0 + bh0[jg2]);
            float z_ = sigmoidf_(gc[H + jg2] + ge[H + jg2] + s1 + bh0[H + jg2]);
            float n_ = tanh_fast(gc[2 * H + jg2] + ge[2 * H + jg2] + r_ * (s2 + bh0[2 * H + jg2]));
            f4 hp = ((const f4*)sh)[A0(jg2 >> 2, fb)];
            float hprev = ((const float*)&hp)[jg2 & 3];
            h0_dst[(size_t)bg2 * H + jg2] = (1.f - z_) * n_ + z_ * hprev;
        }
    } else {
        int lb = blockIdx.x - nb0;
        int jc = lb & 31, bg = lb >> 5;
        int j0 = jc * 16, b0 = bg * 4;
        float* stX = sh;                  // x = y0(t-1)
        float* stH = sh + ST4_SZ * 4;     // h1
        stage4(h0_src + (size_t)b0 * H, stX, tid);
        stage4(h1_src + (size_t)b0 * H, stH, tid);
        __syncthreads();
        int j = tid & 15, ks = (tid >> 4) & 7, m = tid >> 7, jg = j0 + j;
        const ushort* Wm = m ? Wh1bf : Wi1bf;
        const float* stm = m ? stH : stX;
        const uint4* w0 = (const uint4*)(Wm + (size_t)jg * 512) + ks * 8;
        const uint4* w1 = (const uint4*)(Wm + (size_t)(512 + jg) * 512) + ks * 8;
        const uint4* w2 = (const uint4*)(Wm + (size_t)(1024 + jg) * 512) + ks * 8;
        float a0[4] = {}, a1[4] = {}, a2[4] = {};
#pragma unroll
        for (int c = 0; c < 8; ++c) {
            uint4 u0 = w0[c], u1 = w1[c], u2 = w2[c];
            int kq = ks * 16 + c * 2;
#pragma unroll
            for (int b = 0; b < 4; ++b) {
                f4 hA = ((const f4*)stm)[A0(kq, b)];
                f4 hB = ((const f4*)stm)[A0(kq + 1, b)];
                a0[b] += dot8bf(u0, hA, hB);
                a1[b] += dot8bf(u1, hA, hB);
                a2[b] += dot8bf(u2, hA, hB);
            }
        }
        float* part = sh + ST4_SZ * 8;  // 4352 floats in; 256*13 = 3328 floats
        {
            float* p = part + (size_t)tid * 13;
#pragma unroll
            for (int b = 0; b < 4; ++b) { p[b] = a0[b]; p[4 + b] = a1[b]; p[8 + b] = a2[b]; }
        }
        __syncthreads();
        if (tid < 64) {
            int fj = tid & 15, fb = tid >> 4;
            int jg2 = j0 + fj, bg2 = b0 + fb;
            float i0 = 0.f, i1 = 0.f, i2 = 0.f, g0 = 0.f, g1 = 0.f, g2 = 0.f;
#pragma unroll
            for (int k2 = 0; k2 < 8; ++k2) {
                const float* pi = part + (size_t)(k2 * 16 + fj) * 13;
                const float* ph = part + (size_t)((128 + k2 * 16 + fj)) * 13;
                i0 += pi[fb]; i1 += pi[4 + fb]; i2 += pi[8 + fb];
                g0 += ph[fb]; g1 += ph[4 + fb]; g2 += ph[8 + fb];
            }
            float r_ = sigmoidf_(i0 + bi1[jg2] + g0 + bh1[jg2]);
            float z_ = sigmoidf_(i1 + bi1[H + jg2] + g1 + bh1[H + jg2]);
            float n_ = tanh_fast(i2 + bi1[2 * H + jg2] + r_ * (g2 + bh1[2 * H + jg2]));
            f4 hp = ((const f4*)stH)[A0(jg2 >> 2, fb)];
            float hprev = ((const float*)&hp)[jg2 & 3];
            h1_dst[(size_t)bg2 * H + jg2] = (1.f - z_) * n_ + z_ * hprev;
        }
    }
}

__global__ void copy_hidden_kernel(const float* __restrict__ h0, const float* __restrict__ h1,
                                   float* __restrict__ dst) {
    int i = blockIdx.x * 256 + threadIdx.x;
    dst[i] = h0[i];
    dst[BH + i] = h1[i];
}

extern "C" void kernel_launch(void* const* d_in, const int* in_sizes, int n_in,
                              void* d_out_v, int out_size, void* d_ws, size_t ws_size,
                              hipStream_t stream) {
    const float* enc = (const float*)d_in[0];
    const float* hidden = (const float*)d_in[1];
    const float* target = (const float*)d_in[2];
    const float* Wq = (const float*)d_in[3];
    const float* Wk = (const float*)d_in[4];
    const float* wv = (const float*)d_in[5];
    const float* emb_W = (const float*)d_in[6];
    const float* emb_b = (const float*)d_in[7];
    const float* Wi0 = (const float*)d_in[8];
    const float* Wh0 = (const float*)d_in[9];
    const float* bi0 = (const float*)d_in[10];
    const float* bh0 = (const float*)d_in[11];
    const float* Wi1 = (const float*)d_in[12];
    const float* Wh1 = (const float*)d_in[13];
    const float* bi1 = (const float*)d_in[14];
    const float* bh1 = (const float*)d_in[15];
    const float* last_W = (const float*)d_in[16];
    const float* last_b = (const float*)d_in[17];
    const int* tmask = (const int*)d_in[18];

    float* out = (float*)d_out_v;
    float* out_hidden = out + (size_t)STEPS * B * ODIM;
    float* out_attn = out_hidden + (size_t)2 * BH;

    float* ws = (float*)d_ws;
    float* kpT = ws;                      // 2,097,152
    float* WkT = kpT + 2097152;           // 262,144
    float* gi_emb = WkT + 262144;         // 786,432
    float* gi_ctx = gi_emb + 786432;      // 49,152
    float* h0buf = gi_ctx + 49152;        // 32,768 (2x)
    float* h1buf = h0buf + 32768;         // 32,768 (2x)
    float* qbuf = h1buf + 32768;          // 16,384
    float* ctxbuf = qbuf + 16384;         // 16,384
    float* fbuf = ctxbuf + 16384;         // 8,192
    float* inpbuf = fbuf + 8192;          // 16,384
    float* spart = inpbuf + 16384;        // 32,768
    ushort* Wi0bf = (ushort*)(spart + 32768);  // 1,572,864 ushorts
    ushort* Wh0bf = Wi0bf + 1572864;           // 786,432
    ushort* Wi1bf = Wh0bf + 786432;            // 786,432
    ushort* Wh1bf = Wi1bf + 786432;            // 786,432

    cvt4_bf16_kernel<<<3840, 256, 0, stream>>>(Wi0, Wi0bf, Wh0, Wh0bf, Wi1, Wi1bf, Wh1, Wh1bf);
    transpose_kernel<<<dim3(16, 16), 256, 0, stream>>>(Wk, WkT, 512, 512, 512);
    kproj_gemm_kernel<<<dim3(64, 8), 256, 0, stream>>>(enc, WkT, kpT);
    init_kernel<<<B, 512, 0, stream>>>(hidden, emb_W, emb_b, h0buf, h1buf, inpbuf);

    int p0 = 0, p1 = 0;
    for (int i = 0; i < STEPS; ++i) {
        int im1 = (i > 0) ? i - 1 : 0;
        const float* h1cur = h1buf + (size_t)p1 * BH;
        attn1_kernel<<<(i > 0) ? 96 : 64, 256, 0, stream>>>(
            64, h1cur, Wq, qbuf, last_W, last_b, target + (size_t)im1 * B * ODIM,
            tmask + im1 * B, fbuf, out + (size_t)im1 * B * ODIM);
        attn2_kernel<<<(i > 0) ? 288 : 256, 256, 0, stream>>>(qbuf, kpT, wv, spart, fbuf,
                                                              emb_W, emb_b, inpbuf);
        attn3_kernel<<<256, 256, 0, stream>>>(spart, enc, ctxbuf, out_attn + (size_t)i * B * T);
        gi_kernel<<<192, 256, 0, stream>>>(ctxbuf, inpbuf, Wi0bf, bi0, gi_ctx,
                                           gi_emb + (size_t)i * B * G3);
        for (int t = 0; t <= i + 1; ++t) {
            int nb0 = (t <= i) ? 256 : 0;
            int nb1 = (t >= 1) ? 256 : 0;
            int tge = (t <= i) ? t : 0;
            cell_kernel<<<nb0 + nb1, 256, 0, stream>>>(
                nb0, h0buf + (size_t)p0 * BH, h0buf + (size_t)(p0 ^ 1) * BH,
                h1buf + (size_t)p1 * BH, h1buf + (size_t)(p1 ^ 1) * BH,
                gi_emb + (size_t)tge * B * G3, gi_ctx, Wh0bf, bh0, Wi1bf, bi1, Wh1bf, bh1);
            if (nb0) p0 ^= 1;
            if (nb1) p1 ^= 1;
        }
    }
    // final lin (step 15)
    attn1_kernel<<<32, 256, 0, stream>>>(0, h1buf + (size_t)p1 * BH, Wq, qbuf, last_W, last_b,
                                         target + (size_t)15 * B * ODIM, tmask + 15 * B, fbuf,
                                         out + (size_t)15 * B * ODIM);
    copy_hidden_kernel<<<64, 256, 0, stream>>>(h0buf + (size_t)p0 * BH, h1buf + (size_t)p1 * BH,
                                               out_hidden);
}